// Round 1
// baseline (205.874 us; speedup 1.0000x reference)
//
#include <hip/hip_runtime.h>
#include <hip/hip_bf16.h>

// Sizes (static per reference)
#define HGT 56
#define WID 56
#define SPA 3136          // 56*56
#define CCH 256
#define C3  768
#define NH  8
#define HD  32
#define YB  2408448       // 768*3136 per-batch y stride
#define ISTR 43008        // 56*768  (reshaped view: per-i stride)
#define JSTR 768          // per-j stride
#define SCALE_Q 0.17677669529663687f   // 32^-0.5

// ---------------- K1: pointwise qkv GEMM  y1[b][o][s] = sum_c w1[o][c]*x[b][c][s]
__global__ __launch_bounds__(256) void k_pw_qkv(const float* __restrict__ x,
                                                const float* __restrict__ w1,
                                                float* __restrict__ y1) {
    __shared__ float As[16][64];   // [cc][oo]
    __shared__ float Bs[16][64];   // [cc][ss]
    const int tid = threadIdx.x;
    const int tx = tid & 15, ty = tid >> 4;
    const int b = blockIdx.z;
    const int o0 = blockIdx.y * 64;
    const int s0 = blockIdx.x * 64;
    const float* xb = x + b * (CCH * SPA);
    float acc[4][4] = {};
    for (int c0 = 0; c0 < CCH; c0 += 16) {
#pragma unroll
        for (int r = 0; r < 4; ++r) {
            int idx = tid + r * 256;          // 0..1023
            int oo = idx >> 4, cc = idx & 15;
            As[cc][oo] = w1[(o0 + oo) * CCH + c0 + cc];
        }
#pragma unroll
        for (int r = 0; r < 4; ++r) {
            int idx = tid + r * 256;
            int cc = idx >> 6, ss = idx & 63;
            Bs[cc][ss] = xb[(c0 + cc) * SPA + s0 + ss];
        }
        __syncthreads();
#pragma unroll
        for (int cc = 0; cc < 16; ++cc) {
            float a[4], bb[4];
#pragma unroll
            for (int i = 0; i < 4; ++i) a[i] = As[cc][ty * 4 + i];
#pragma unroll
            for (int j = 0; j < 4; ++j) bb[j] = Bs[cc][tx * 4 + j];
#pragma unroll
            for (int i = 0; i < 4; ++i)
#pragma unroll
                for (int j = 0; j < 4; ++j)
                    acc[i][j] += a[i] * bb[j];
        }
        __syncthreads();
    }
    float* yb = y1 + b * YB;
#pragma unroll
    for (int i = 0; i < 4; ++i)
#pragma unroll
        for (int j = 0; j < 4; ++j)
            yb[(o0 + ty * 4 + i) * SPA + s0 + tx * 4 + j] = acc[i][j];
}

// ---------------- K2: depthwise 3x3 SAME (cross-correlation, zero pad)
__global__ __launch_bounds__(256) void k_dw(const float* __restrict__ y1,
                                            const float* __restrict__ w2,
                                            float* __restrict__ y2) {
    int idx = blockIdx.x * 256 + threadIdx.x;   // total 2*768*3136 = 4816896 (exact)
    int s = idx % SPA;
    int bc = idx / SPA;            // b*768 + ch
    int ch = bc % C3;
    int h = s / WID, w = s % WID;
    const float* in = y1 + bc * SPA;
    const float* wt = w2 + ch * 9;
    float acc = 0.f;
#pragma unroll
    for (int dh = -1; dh <= 1; ++dh) {
        int hh = h + dh;
        if (hh < 0 || hh >= HGT) continue;
#pragma unroll
        for (int dw = -1; dw <= 1; ++dw) {
            int ww = w + dw;
            if (ww < 0 || ww >= WID) continue;
            acc += wt[(dh + 1) * 3 + (dw + 1)] * in[hh * WID + ww];
        }
    }
    y2[idx] = acc;
}

// ---------------- K3: 2-split NATTEN attention (K=7; D=1 heads 0-3, D=2 heads 4-7)
// one wave per (b,head,i,j); 4 waves/block along j
__global__ __launch_bounds__(256) void k_attn(const float* __restrict__ y2,
                                              const float* __restrict__ rpb0,
                                              const float* __restrict__ rpb1,
                                              float* __restrict__ opre) {
    __shared__ float wsm[4][64];
    const int lane = threadIdx.x & 63;
    const int wid = threadIdx.x >> 6;
    const int j = blockIdx.x * 4 + wid;
    const int i = blockIdx.y;
    const int bh = blockIdx.z;
    const int b = bh >> 3, head = bh & 7;
    const int split = head >> 2;
    const int D = 1 + split;

    int wsi, wsj, pbi, pbj;
    if (split == 0) {
        wsi = (i < 3) ? 0 : ((i > 52) ? 49 : i - 3);
        wsj = (j < 3) ? 0 : ((j > 52) ? 49 : j - 3);
        pbi = (i < 3) ? 6 - i : ((i > 52) ? 55 - i : 3);
        pbj = (j < 3) ? 6 - j : ((j > 52) ? 55 - j : 3);
    } else {
        wsi = (i < 6) ? (i & 1) : ((i >= 50) ? 42 + (i & 1) : i - 6);
        wsj = (j < 6) ? (j & 1) : ((j >= 50) ? 42 + (j & 1) : j - 6);
        pbi = (i < 6) ? 6 - (i >> 1) : ((i >= 50) ? (55 - i) >> 1 : 3);
        pbj = (j < 6) ? 6 - (j >> 1) : ((j >= 50) ? (55 - j) >> 1 : 3);
    }

    const float* ybase = y2 + b * YB + head * HD;
    // load q (uniform per wave, broadcast)
    const float4* qp = (const float4*)(ybase + i * ISTR + j * JSTR);
    float4 q[8];
#pragma unroll
    for (int r = 0; r < 8; ++r) q[r] = qp[r];

    const int u = lane / 7;
    const int v = lane - u * 7;
    const bool act = lane < 49;
    float logit = -1e30f;
    if (act) {
        const int ki = wsi + D * u, kj = wsj + D * v;
        const float4* kp = (const float4*)(ybase + 256 + ki * ISTR + kj * JSTR);
        float acc = 0.f;
#pragma unroll
        for (int r = 0; r < 8; ++r) {
            float4 kk = kp[r];
            acc += q[r].x * kk.x + q[r].y * kk.y + q[r].z * kk.z + q[r].w * kk.w;
        }
        acc *= SCALE_Q;
        float bias = split ? rpb1[(head - 4) * 169 + (pbi + u) * 13 + (pbj + v)]
                           : rpb0[head * 169 + (pbi + u) * 13 + (pbj + v)];
        logit = acc + bias;
    }
    // 64-lane softmax
    float m = logit;
#pragma unroll
    for (int off = 32; off; off >>= 1) m = fmaxf(m, __shfl_xor(m, off));
    float e = act ? __expf(logit - m) : 0.f;
    float ssum = e;
#pragma unroll
    for (int off = 32; off; off >>= 1) ssum += __shfl_xor(ssum, off);
    float wgt = e / ssum;
    if (act) wsm[wid][lane] = wgt;
    __syncthreads();

    // PV: lanes = 2 halves x 32 dims
    const int d = lane & 31, half = lane >> 5;
    const float* vbase = ybase + 512 + d;
    float acc = 0.f;
    for (int p = half; p < 49; p += 2) {
        int uu = p / 7;
        int vv = p - uu * 7;
        int ki = wsi + D * uu, kj = wsj + D * vv;
        acc += wsm[wid][p] * vbase[ki * ISTR + kj * JSTR];
    }
    acc += __shfl_xor(acc, 32);
    if (lane < 32) {
        opre[b * (SPA * CCH) + (i * WID + j) * CCH + head * HD + d] = acc;
    }
}

// ---------------- K4: proj GEMM  out[b][o][s] = sum_c wp[o][c]*opre[b][s][c]
__global__ __launch_bounds__(256) void k_proj(const float* __restrict__ opre,
                                              const float* __restrict__ wp,
                                              float* __restrict__ out) {
    __shared__ float As[16][64];   // [cc][oo]
    __shared__ float Bs[16][64];   // [cc][ss]
    const int tid = threadIdx.x;
    const int tx = tid & 15, ty = tid >> 4;
    const int b = blockIdx.z;
    const int o0 = blockIdx.y * 64;
    const int s0 = blockIdx.x * 64;
    const float* ob = opre + b * (SPA * CCH);
    float acc[4][4] = {};
    for (int c0 = 0; c0 < CCH; c0 += 16) {
#pragma unroll
        for (int r = 0; r < 4; ++r) {
            int idx = tid + r * 256;
            int oo = idx >> 4, cc = idx & 15;
            As[cc][oo] = wp[(o0 + oo) * CCH + c0 + cc];
        }
#pragma unroll
        for (int r = 0; r < 4; ++r) {
            int idx = tid + r * 256;
            int ss = idx >> 4, cc = idx & 15;
            Bs[cc][ss] = ob[(s0 + ss) * CCH + c0 + cc];
        }
        __syncthreads();
#pragma unroll
        for (int cc = 0; cc < 16; ++cc) {
            float a[4], bb[4];
#pragma unroll
            for (int i = 0; i < 4; ++i) a[i] = As[cc][ty * 4 + i];
#pragma unroll
            for (int j = 0; j < 4; ++j) bb[j] = Bs[cc][tx * 4 + j];
#pragma unroll
            for (int i = 0; i < 4; ++i)
#pragma unroll
                for (int j = 0; j < 4; ++j)
                    acc[i][j] += a[i] * bb[j];
        }
        __syncthreads();
    }
    float* outb = out + b * (CCH * SPA);
#pragma unroll
    for (int i = 0; i < 4; ++i)
#pragma unroll
        for (int j = 0; j < 4; ++j)
            outb[(o0 + ty * 4 + i) * SPA + s0 + tx * 4 + j] = acc[i][j];
}

extern "C" void kernel_launch(void* const* d_in, const int* in_sizes, int n_in,
                              void* d_out, int out_size, void* d_ws, size_t ws_size,
                              hipStream_t stream) {
    const float* x    = (const float*)d_in[0];
    const float* w1   = (const float*)d_in[1];
    const float* w2   = (const float*)d_in[2];
    const float* rpb0 = (const float*)d_in[3];
    const float* rpb1 = (const float*)d_in[4];
    const float* wp   = (const float*)d_in[5];
    float* out = (float*)d_out;

    float* y1   = (float*)d_ws;                 // [2][768][3136]
    float* y2   = y1 + 2 * YB;                  // [2][768][3136]
    float* opre = y2 + 2 * YB;                  // [2][3136][256]

    // K1: qkv pointwise GEMM
    k_pw_qkv<<<dim3(SPA / 64, C3 / 64, 2), 256, 0, stream>>>(x, w1, y1);
    // K2: depthwise 3x3
    k_dw<<<dim3((2 * C3 * SPA) / 256), 256, 0, stream>>>(y1, w2, y2);
    // K3: attention
    k_attn<<<dim3(WID / 4, HGT, 2 * NH), 256, 0, stream>>>(y2, rpb0, rpb1, opre);
    // K4: projection GEMM
    k_proj<<<dim3(SPA / 64, CCH / 64, 2), 256, 0, stream>>>(opre, wp, out);
}

// Round 2
// 167.467 us; speedup vs baseline: 1.2293x; 1.2293x over previous
//
#include <hip/hip_runtime.h>
#include <hip/hip_bf16.h>

// Sizes (static per reference)
#define HGT 56
#define WID 56
#define SPA 3136          // 56*56
#define CCH 256
#define C3  768
#define NH  8
#define HD  32
#define YB  2408448       // 768*3136 per-batch y stride
#define ISTR 43008        // 56*768  (reshaped view: per-i stride)
#define JSTR 768          // per-j stride
#define SCALE_Q 0.17677669529663687f   // 32^-0.5

// ---------------- K1: pointwise qkv GEMM  y1[b][o][s] = sum_c w1[o][c]*x[b][c][s]
__global__ __launch_bounds__(256) void k_pw_qkv(const float* __restrict__ x,
                                                const float* __restrict__ w1,
                                                float* __restrict__ y1) {
    __shared__ float As[16][64];   // [cc][oo]
    __shared__ float Bs[16][64];   // [cc][ss]
    const int tid = threadIdx.x;
    const int tx = tid & 15, ty = tid >> 4;
    const int b = blockIdx.z;
    const int o0 = blockIdx.y * 64;
    const int s0 = blockIdx.x * 64;
    const float* xb = x + b * (CCH * SPA);
    float acc[4][4] = {};
    for (int c0 = 0; c0 < CCH; c0 += 16) {
#pragma unroll
        for (int r = 0; r < 4; ++r) {
            int idx = tid + r * 256;          // 0..1023
            int oo = idx >> 4, cc = idx & 15;
            As[cc][oo] = w1[(o0 + oo) * CCH + c0 + cc];
        }
#pragma unroll
        for (int r = 0; r < 4; ++r) {
            int idx = tid + r * 256;
            int cc = idx >> 6, ss = idx & 63;
            Bs[cc][ss] = xb[(c0 + cc) * SPA + s0 + ss];
        }
        __syncthreads();
#pragma unroll
        for (int cc = 0; cc < 16; ++cc) {
            float a[4], bb[4];
#pragma unroll
            for (int i = 0; i < 4; ++i) a[i] = As[cc][ty * 4 + i];
#pragma unroll
            for (int j = 0; j < 4; ++j) bb[j] = Bs[cc][tx * 4 + j];
#pragma unroll
            for (int i = 0; i < 4; ++i)
#pragma unroll
                for (int j = 0; j < 4; ++j)
                    acc[i][j] += a[i] * bb[j];
        }
        __syncthreads();
    }
    float* yb = y1 + b * YB;
#pragma unroll
    for (int i = 0; i < 4; ++i)
#pragma unroll
        for (int j = 0; j < 4; ++j)
            yb[(o0 + ty * 4 + i) * SPA + s0 + tx * 4 + j] = acc[i][j];
}

// ---------------- K2: depthwise 3x3 SAME (cross-correlation, zero pad)
__global__ __launch_bounds__(256) void k_dw(const float* __restrict__ y1,
                                            const float* __restrict__ w2,
                                            float* __restrict__ y2) {
    int idx = blockIdx.x * 256 + threadIdx.x;   // total 2*768*3136 = 4816896 (exact)
    int s = idx % SPA;
    int bc = idx / SPA;            // b*768 + ch
    int ch = bc % C3;
    int h = s / WID, w = s % WID;
    const float* in = y1 + bc * SPA;
    const float* wt = w2 + ch * 9;
    float acc = 0.f;
#pragma unroll
    for (int dh = -1; dh <= 1; ++dh) {
        int hh = h + dh;
        if (hh < 0 || hh >= HGT) continue;
#pragma unroll
        for (int dw = -1; dw <= 1; ++dw) {
            int ww = w + dw;
            if (ww < 0 || ww >= WID) continue;
            acc += wt[(dh + 1) * 3 + (dw + 1)] * in[hh * WID + ww];
        }
    }
    y2[idx] = acc;
}

// ---------------- K3 v2: per-(i, b*head) block; K rows staged in LDS;
// table-driven unrolled PV; no division in hot loop.
template<int D>
__device__ __forceinline__ void attn_body(float* __restrict__ Kl,
                                          float* __restrict__ biasl,
                                          float (*__restrict__ wsm)[64],
                                          int* __restrict__ voff,
                                          const float* __restrict__ y2,
                                          const float* __restrict__ rpb,
                                          float* __restrict__ opre,
                                          int b, int head, int i, int hsub) {
    const int tid = threadIdx.x;
    const int lane = tid & 63, wid = tid >> 6;

    int wsi, pbi;
    if (D == 1) {
        wsi = (i < 3) ? 0 : ((i > 52) ? 49 : i - 3);
        pbi = (i < 3) ? 6 - i : ((i > 52) ? 55 - i : 3);
    } else {
        wsi = (i < 6) ? (i & 1) : ((i >= 50) ? 42 + (i & 1) : i - 6);
        pbi = (i < 6) ? 6 - (i >> 1) : ((i >= 50) ? (55 - i) >> 1 : 3);
    }

    const float* ybase = y2 + b * YB + head * HD;

    // ---- stage the 7 K rows: Kl[(kj*7+u)*36 + d], 144B row stride (16B aligned,
    // bank-spread: start bank = 4*(7*kj+u) mod 32)
    const float* kbase = ybase + CCH + wsi * ISTR;   // K = t index 1
    for (int f = tid; f < 3136; f += 256) {
        int u = f / 448;                 // 448 = 56 cols * 8 float4
        int rem = f - u * 448;
        int kj = rem >> 3;
        int r  = rem & 7;
        const float4 src = *((const float4*)(kbase + u * (D * ISTR) + kj * JSTR) + r);
        *(float4*)&Kl[(kj * 7 + u) * 36 + r * 4] = src;
    }
    if (tid < 169) biasl[tid] = rpb[hsub * 169 + tid];
    if (tid < 50) {
        int uu = tid / 7, vv = tid - uu * 7;
        voff[tid] = (tid < 49) ? D * (uu * ISTR + vv * JSTR) : 0;
    }
    __syncthreads();

    // per-lane constants
    int u = lane / 7, v = lane - u * 7;
    const bool act = lane < 49;
    if (!act) { u = 0; v = 0; }
    const int kconst = (D * v * 7 + u) * 36;   // + wsj*252 at runtime
    const int bconst = u * 13 + v + pbi * 13;
    const int d = lane & 31, half = lane >> 5;
    const float* vbS = ybase + 2 * CCH + wsi * ISTR;  // V rows base (sgpr)

    for (int jj = 0; jj < 14; ++jj) {
        const int j = wid * 14 + jj;
        int wsj, pbj;
        if (D == 1) {
            wsj = (j < 3) ? 0 : ((j > 52) ? 49 : j - 3);
            pbj = (j < 3) ? 6 - j : ((j > 52) ? 55 - j : 3);
        } else {
            wsj = (j < 6) ? (j & 1) : ((j >= 50) ? 42 + (j & 1) : j - 6);
            pbj = (j < 6) ? 6 - (j >> 1) : ((j >= 50) ? (55 - j) >> 1 : 3);
        }

        // q: uniform 8x float4 (L2-hot)
        const float4* qp = (const float4*)(ybase + i * ISTR + j * JSTR);
        float4 q[8];
#pragma unroll
        for (int r = 0; r < 8; ++r) q[r] = qp[r];

        // QK from LDS
        const float* kp = &Kl[wsj * 252 + kconst];
        float acc = 0.f;
#pragma unroll
        for (int r = 0; r < 8; ++r) {
            float4 kk = *(const float4*)(kp + r * 4);
            acc += q[r].x * kk.x + q[r].y * kk.y + q[r].z * kk.z + q[r].w * kk.w;
        }
        float logit = act ? (acc * SCALE_Q + biasl[bconst + pbj]) : -1e30f;

        // 64-lane softmax
        float m = logit;
#pragma unroll
        for (int off = 32; off; off >>= 1) m = fmaxf(m, __shfl_xor(m, off));
        float e = act ? __expf(logit - m) : 0.f;
        float ssum = e;
#pragma unroll
        for (int off = 32; off; off >>= 1) ssum += __shfl_xor(ssum, off);
        const float wgt = e * __frcp_rn(ssum);
        wsm[wid][lane] = wgt;   // lanes >=49 write 0; same-wave LDS is in-order

        // PV: 25 uniform unrolled steps per half; slot 49 is weight-0/offset-0 pad
        const unsigned pixoff = (unsigned)(wsj * JSTR + d);
        float oacc = 0.f;
#pragma unroll
        for (int t = 0; t < 25; ++t) {
            const int p = half * 25 + t;
            const float w = wsm[wid][p];
            const unsigned off = pixoff + (unsigned)voff[p];
            oacc += w * vbS[off];
        }
        oacc += __shfl_xor(oacc, 32);
        if (half == 0)
            opre[b * (SPA * CCH) + (i * WID + j) * CCH + head * HD + d] = oacc;
    }
}

__global__ __launch_bounds__(256) void k_attn2(const float* __restrict__ y2,
                                               const float* __restrict__ rpb0,
                                               const float* __restrict__ rpb1,
                                               float* __restrict__ opre) {
    __shared__ float Kl[14112];        // 56*7*36
    __shared__ float biasl[169];
    __shared__ float wsm[4][64];
    __shared__ int   voff[52];
    const int i = blockIdx.x;
    const int bh = blockIdx.y;
    const int b = bh >> 3, head = bh & 7;
    if (head < 4)
        attn_body<1>(Kl, biasl, wsm, voff, y2, rpb0, opre, b, head, i, head);
    else
        attn_body<2>(Kl, biasl, wsm, voff, y2, rpb1, opre, b, head, i, head - 4);
}

// ---------------- K4: proj GEMM  out[b][o][s] = sum_c wp[o][c]*opre[b][s][c]
__global__ __launch_bounds__(256) void k_proj(const float* __restrict__ opre,
                                              const float* __restrict__ wp,
                                              float* __restrict__ out) {
    __shared__ float As[16][64];   // [cc][oo]
    __shared__ float Bs[16][64];   // [cc][ss]
    const int tid = threadIdx.x;
    const int tx = tid & 15, ty = tid >> 4;
    const int b = blockIdx.z;
    const int o0 = blockIdx.y * 64;
    const int s0 = blockIdx.x * 64;
    const float* ob = opre + b * (SPA * CCH);
    float acc[4][4] = {};
    for (int c0 = 0; c0 < CCH; c0 += 16) {
#pragma unroll
        for (int r = 0; r < 4; ++r) {
            int idx = tid + r * 256;
            int oo = idx >> 4, cc = idx & 15;
            As[cc][oo] = wp[(o0 + oo) * CCH + c0 + cc];
        }
#pragma unroll
        for (int r = 0; r < 4; ++r) {
            int idx = tid + r * 256;
            int ss = idx >> 4, cc = idx & 15;
            Bs[cc][ss] = ob[(s0 + ss) * CCH + c0 + cc];
        }
        __syncthreads();
#pragma unroll
        for (int cc = 0; cc < 16; ++cc) {
            float a[4], bb[4];
#pragma unroll
            for (int i = 0; i < 4; ++i) a[i] = As[cc][ty * 4 + i];
#pragma unroll
            for (int j = 0; j < 4; ++j) bb[j] = Bs[cc][tx * 4 + j];
#pragma unroll
            for (int i = 0; i < 4; ++i)
#pragma unroll
                for (int j = 0; j < 4; ++j)
                    acc[i][j] += a[i] * bb[j];
        }
        __syncthreads();
    }
    float* outb = out + b * (CCH * SPA);
#pragma unroll
    for (int i = 0; i < 4; ++i)
#pragma unroll
        for (int j = 0; j < 4; ++j)
            outb[(o0 + ty * 4 + i) * SPA + s0 + tx * 4 + j] = acc[i][j];
}

extern "C" void kernel_launch(void* const* d_in, const int* in_sizes, int n_in,
                              void* d_out, int out_size, void* d_ws, size_t ws_size,
                              hipStream_t stream) {
    const float* x    = (const float*)d_in[0];
    const float* w1   = (const float*)d_in[1];
    const float* w2   = (const float*)d_in[2];
    const float* rpb0 = (const float*)d_in[3];
    const float* rpb1 = (const float*)d_in[4];
    const float* wp   = (const float*)d_in[5];
    float* out = (float*)d_out;

    float* y1   = (float*)d_ws;                 // [2][768][3136]
    float* y2   = y1 + 2 * YB;                  // [2][768][3136]
    float* opre = y2 + 2 * YB;                  // [2][3136][256]

    // K1: qkv pointwise GEMM
    k_pw_qkv<<<dim3(SPA / 64, C3 / 64, 2), 256, 0, stream>>>(x, w1, y1);
    // K2: depthwise 3x3
    k_dw<<<dim3((2 * C3 * SPA) / 256), 256, 0, stream>>>(y1, w2, y2);
    // K3: attention v2
    k_attn2<<<dim3(HGT, 2 * NH), 256, 0, stream>>>(y2, rpb0, rpb1, opre);
    // K4: projection GEMM
    k_proj<<<dim3(SPA / 64, CCH / 64, 2), 256, 0, stream>>>(opre, wp, out);
}

// Round 4
// 111.848 us; speedup vs baseline: 1.8407x; 1.4973x over previous
//
#include <hip/hip_runtime.h>
#include <hip/hip_bf16.h>

// Sizes (static per reference)
#define HGT 56
#define WID 56
#define SPA 3136          // 56*56
#define CCH 256
#define C3  768
#define NH  8
#define HD  32
#define YB  2408448       // 768*3136 per-batch y stride
#define ISTR 43008        // 56*768  (reshaped NCHW-flat view: per-i stride)
#define JSTR 768          // per-j stride
#define SCALE_Q 0.17677669529663687f   // 32^-0.5

typedef __attribute__((ext_vector_type(8))) short short8;
typedef __attribute__((ext_vector_type(4))) float f32x4;

static __device__ __forceinline__ unsigned short f2bf_bits(float f) {
    __hip_bfloat16 h = __float2bfloat16(f);
    union { __hip_bfloat16 h; unsigned short u; } cv; cv.h = h; return cv.u;
}

// ---------------- cvt weights to bf16: w1 (768*256) then wp (256*256)
__global__ __launch_bounds__(256) void k_cvt_w(const float* __restrict__ w1,
                                               const float* __restrict__ wp,
                                               __hip_bfloat16* __restrict__ w1b,
                                               __hip_bfloat16* __restrict__ wpb) {
    int i = (blockIdx.x * 256 + threadIdx.x) * 4;   // 262144 total, exact
    const float* src;
    __hip_bfloat16* dst;
    if (i < 196608) { src = w1 + i; dst = w1b + i; }
    else            { src = wp + (i - 196608); dst = wpb + (i - 196608); }
    float4 v = *(const float4*)src;
    ushort4 u;
    u.x = f2bf_bits(v.x); u.y = f2bf_bits(v.y);
    u.z = f2bf_bits(v.z); u.w = f2bf_bits(v.w);
    *(ushort4*)dst = u;
}

// ---------------- cvt+transpose x: [b][c][s] f32 -> xT [b][s][c] bf16
__global__ __launch_bounds__(256) void k_cvt_xT(const float* __restrict__ x,
                                                __hip_bfloat16* __restrict__ xT) {
    __shared__ __align__(16) __hip_bfloat16 Sl[64][80];   // 160B rows (16B mult)
    const int t = threadIdx.x;
    const int b = blockIdx.z, c0 = blockIdx.y * 64, s0 = blockIdx.x * 64;
    const float* xb = x + (size_t)b * (CCH * SPA);
    const int sq = (t & 15) * 4, cq = (t >> 4) * 4;   // 4x4 micro-tile
    float4 r[4];
#pragma unroll
    for (int rr = 0; rr < 4; ++rr)
        r[rr] = *(const float4*)&xb[(size_t)(c0 + cq + rr) * SPA + s0 + sq];
#pragma unroll
    for (int j = 0; j < 4; ++j) {
        ushort4 u;
        u.x = f2bf_bits(((const float*)&r[0])[j]);
        u.y = f2bf_bits(((const float*)&r[1])[j]);
        u.z = f2bf_bits(((const float*)&r[2])[j]);
        u.w = f2bf_bits(((const float*)&r[3])[j]);
        *(ushort4*)&Sl[sq + j][cq] = u;
    }
    __syncthreads();
    const int srow = t >> 2, cslot = t & 3;
    __hip_bfloat16* dst = &xT[(size_t)b * SPA * CCH + (size_t)(s0 + srow) * CCH + c0];
    short8 v0 = *(const short8*)&Sl[srow][cslot * 8];
    short8 v1 = *(const short8*)&Sl[srow][(cslot + 4) * 8];
    *(short8*)&dst[cslot * 8] = v0;
    *(short8*)&dst[(cslot + 4) * 8] = v1;
}

// ---------------- bf16 MFMA GEMM: C[b][o][s] = sum_c A[o][c] * B[b][s][c]
// 64x64 tile, BK=64, 4 waves x (2x2) 16x16x32 frags, global_load_lds staging
// with pre-swizzled source (XOR bank swizzle), conflict-free ds_read_b128.
__global__ __launch_bounds__(256) void k_gemm(const __hip_bfloat16* __restrict__ A,
                                              const __hip_bfloat16* __restrict__ B,
                                              float* __restrict__ C, int M) {
    __shared__ __align__(16) short sA[4096];   // 64 rows x 128B, swizzled
    __shared__ __align__(16) short sB[4096];
    const int t = threadIdx.x;
    const int lane = t & 63, w = t >> 6;
    const int s0 = blockIdx.x * 64, o0 = blockIdx.y * 64, b = blockIdx.z;
    const __hip_bfloat16* Bb = B + (size_t)b * SPA * CCH;

    // staging: thread t covers row srow=t>>3 (and srow+32), 16B slot (t&7);
    // LDS byte t*16 (= row*128 + slot*16); inverse swizzle on SOURCE:
    // global c-group = (t&7) ^ (srow&7)   ((srow+32)&7 == srow&7)
    const int srow = t >> 3;
    const int scol = (t & 7) ^ (srow & 7);
    const char* gA = (const char*)(A  + (size_t)(o0 + srow) * CCH) + scol * 16;
    const char* gB = (const char*)(Bb + (size_t)(s0 + srow) * CCH) + scol * 16;
    char* lA = (char*)sA + w * 1024;        // rows 0..31 half
    char* lB = (char*)sB + w * 1024;

    const int wm = w >> 1, wn = w & 1;
    const int lr = lane & 15, kh = lane >> 4;
    const int ar0 = wm * 32 + lr, ar1 = ar0 + 16;
    const int br0 = wn * 32 + lr, br1 = br0 + 16;

    f32x4 acc[2][2] = {};
    for (int kt = 0; kt < 4; ++kt) {
        __builtin_amdgcn_global_load_lds(
            (const __attribute__((address_space(1))) void*)(gA + kt * 128),
            (__attribute__((address_space(3))) void*)lA, 16, 0, 0);
        __builtin_amdgcn_global_load_lds(
            (const __attribute__((address_space(1))) void*)(gA + 16384 + kt * 128),
            (__attribute__((address_space(3))) void*)(lA + 4096), 16, 0, 0);
        __builtin_amdgcn_global_load_lds(
            (const __attribute__((address_space(1))) void*)(gB + kt * 128),
            (__attribute__((address_space(3))) void*)lB, 16, 0, 0);
        __builtin_amdgcn_global_load_lds(
            (const __attribute__((address_space(1))) void*)(gB + 16384 + kt * 128),
            (__attribute__((address_space(3))) void*)(lB + 4096), 16, 0, 0);
        __syncthreads();
#pragma unroll
        for (int kk = 0; kk < 2; ++kk) {
            const int kg = (kk << 2) | kh;
            short8 a0 = *(const short8*)&sA[(ar0 * 128 + ((kg ^ (ar0 & 7)) << 4)) >> 1];
            short8 a1 = *(const short8*)&sA[(ar1 * 128 + ((kg ^ (ar1 & 7)) << 4)) >> 1];
            short8 b0 = *(const short8*)&sB[(br0 * 128 + ((kg ^ (br0 & 7)) << 4)) >> 1];
            short8 b1 = *(const short8*)&sB[(br1 * 128 + ((kg ^ (br1 & 7)) << 4)) >> 1];
            acc[0][0] = __builtin_amdgcn_mfma_f32_16x16x32_bf16(a0, b0, acc[0][0], 0, 0, 0);
            acc[0][1] = __builtin_amdgcn_mfma_f32_16x16x32_bf16(a0, b1, acc[0][1], 0, 0, 0);
            acc[1][0] = __builtin_amdgcn_mfma_f32_16x16x32_bf16(a1, b0, acc[1][0], 0, 0, 0);
            acc[1][1] = __builtin_amdgcn_mfma_f32_16x16x32_bf16(a1, b1, acc[1][1], 0, 0, 0);
        }
        __syncthreads();
    }
    float* Cb = C + (size_t)b * M * SPA;
#pragma unroll
    for (int mi = 0; mi < 2; ++mi)
#pragma unroll
        for (int ni = 0; ni < 2; ++ni) {
            const int r0 = o0 + wm * 32 + mi * 16 + kh * 4;
            const int cc = s0 + wn * 32 + ni * 16 + lr;
#pragma unroll
            for (int q = 0; q < 4; ++q)
                Cb[(size_t)(r0 + q) * SPA + cc] = acc[mi][ni][q];
        }
}

// ---------------- K2: depthwise 3x3 SAME (cross-correlation, zero pad)
__global__ __launch_bounds__(256) void k_dw(const float* __restrict__ y1,
                                            const float* __restrict__ w2,
                                            float* __restrict__ y2) {
    int idx = blockIdx.x * 256 + threadIdx.x;
    int s = idx % SPA;
    int bc = idx / SPA;
    int ch = bc % C3;
    int h = s / WID, w = s % WID;
    const float* in = y1 + (size_t)bc * SPA;
    const float* wt = w2 + ch * 9;
    float acc = 0.f;
#pragma unroll
    for (int dh = -1; dh <= 1; ++dh) {
        int hh = h + dh;
        if (hh < 0 || hh >= HGT) continue;
#pragma unroll
        for (int dw = -1; dw <= 1; ++dw) {
            int ww = w + dw;
            if (ww < 0 || ww >= WID) continue;
            acc += wt[(dh + 1) * 3 + (dw + 1)] * in[hh * WID + ww];
        }
    }
    y2[idx] = acc;
}

// ---------------- K3: NATTEN attention (K=7; D=1 heads 0-3, D=2 heads 4-7)
template<int D>
__device__ __forceinline__ void attn_body(float* __restrict__ Kl,
                                          float* __restrict__ biasl,
                                          float (*__restrict__ wsm)[64],
                                          int* __restrict__ voff,
                                          const float* __restrict__ y2,
                                          const float* __restrict__ rpb,
                                          __hip_bfloat16* __restrict__ opre,
                                          int b, int head, int i, int hsub) {
    const int tid = threadIdx.x;
    const int lane = tid & 63, wid = tid >> 6;

    int wsi, pbi;
    if (D == 1) {
        wsi = (i < 3) ? 0 : ((i > 52) ? 49 : i - 3);
        pbi = (i < 3) ? 6 - i : ((i > 52) ? 55 - i : 3);
    } else {
        wsi = (i < 6) ? (i & 1) : ((i >= 50) ? 42 + (i & 1) : i - 6);
        pbi = (i < 6) ? 6 - (i >> 1) : ((i >= 50) ? (55 - i) >> 1 : 3);
    }

    const float* ybase = y2 + (size_t)b * YB + head * HD;

    const float* kbase = ybase + CCH + wsi * ISTR;
    for (int f = tid; f < 3136; f += 256) {
        int u = f / 448;
        int rem = f - u * 448;
        int kj = rem >> 3;
        int r  = rem & 7;
        const float4 src = *((const float4*)(kbase + u * (D * ISTR) + kj * JSTR) + r);
        *(float4*)&Kl[(kj * 7 + u) * 36 + r * 4] = src;
    }
    if (tid < 169) biasl[tid] = rpb[hsub * 169 + tid];
    if (tid < 50) {
        int uu = tid / 7, vv = tid - uu * 7;
        voff[tid] = (tid < 49) ? D * (uu * ISTR + vv * JSTR) : 0;
    }
    __syncthreads();

    int u = lane / 7, v = lane - u * 7;
    const bool act = lane < 49;
    if (!act) { u = 0; v = 0; }
    const int kconst = (D * v * 7 + u) * 36;
    const int bconst = u * 13 + v + pbi * 13;
    const int d = lane & 31, half = lane >> 5;
    const float* vbS = ybase + 2 * CCH + wsi * ISTR;

    for (int jj = 0; jj < 14; ++jj) {
        const int j = wid * 14 + jj;
        int wsj, pbj;
        if (D == 1) {
            wsj = (j < 3) ? 0 : ((j > 52) ? 49 : j - 3);
            pbj = (j < 3) ? 6 - j : ((j > 52) ? 55 - j : 3);
        } else {
            wsj = (j < 6) ? (j & 1) : ((j >= 50) ? 42 + (j & 1) : j - 6);
            pbj = (j < 6) ? 6 - (j >> 1) : ((j >= 50) ? (55 - j) >> 1 : 3);
        }

        const float4* qp = (const float4*)(ybase + i * ISTR + j * JSTR);
        float4 q[8];
#pragma unroll
        for (int r = 0; r < 8; ++r) q[r] = qp[r];

        const float* kp = &Kl[wsj * 252 + kconst];
        float acc = 0.f;
#pragma unroll
        for (int r = 0; r < 8; ++r) {
            float4 kk = *(const float4*)(kp + r * 4);
            acc += q[r].x * kk.x + q[r].y * kk.y + q[r].z * kk.z + q[r].w * kk.w;
        }
        float logit = act ? (acc * SCALE_Q + biasl[bconst + pbj]) : -1e30f;

        float m = logit;
#pragma unroll
        for (int off = 32; off; off >>= 1) m = fmaxf(m, __shfl_xor(m, off));
        float e = act ? __expf(logit - m) : 0.f;
        float ssum = e;
#pragma unroll
        for (int off = 32; off; off >>= 1) ssum += __shfl_xor(ssum, off);
        const float wgt = e * __frcp_rn(ssum);
        wsm[wid][lane] = wgt;

        const unsigned pixoff = (unsigned)(wsj * JSTR + d);
        float oacc = 0.f;
#pragma unroll
        for (int tt = 0; tt < 25; ++tt) {
            const int p = half * 25 + tt;
            const float wv = wsm[wid][p];
            const unsigned off = pixoff + (unsigned)voff[p];
            oacc += wv * vbS[off];
        }
        oacc += __shfl_xor(oacc, 32);
        if (half == 0)
            opre[(size_t)b * (SPA * CCH) + (size_t)(i * WID + j) * CCH + head * HD + d] =
                __float2bfloat16(oacc);
    }
}

__global__ __launch_bounds__(256) void k_attn2(const float* __restrict__ y2,
                                               const float* __restrict__ rpb0,
                                               const float* __restrict__ rpb1,
                                               __hip_bfloat16* __restrict__ opre) {
    __shared__ float Kl[14112];
    __shared__ float biasl[169];
    __shared__ float wsm[4][64];
    __shared__ int   voff[52];
    const int i = blockIdx.x;
    const int bh = blockIdx.y;
    const int b = bh >> 3, head = bh & 7;
    if (head < 4)
        attn_body<1>(Kl, biasl, wsm, voff, y2, rpb0, opre, b, head, i, head);
    else
        attn_body<2>(Kl, biasl, wsm, voff, y2, rpb1, opre, b, head, i, head - 4);
}

extern "C" void kernel_launch(void* const* d_in, const int* in_sizes, int n_in,
                              void* d_out, int out_size, void* d_ws, size_t ws_size,
                              hipStream_t stream) {
    const float* x    = (const float*)d_in[0];
    const float* w1   = (const float*)d_in[1];
    const float* w2   = (const float*)d_in[2];
    const float* rpb0 = (const float*)d_in[3];
    const float* rpb1 = (const float*)d_in[4];
    const float* wp   = (const float*)d_in[5];
    float* out = (float*)d_out;

    float* p = (float*)d_ws;
    float* y1 = p;                       // [2][768][3136] f32
    float* y2 = p + 2 * YB;              // [2][768][3136] f32
    // region3: xT (lives cvt->K1) aliases opre (lives K3->K4): both [2][3136][256] bf16
    __hip_bfloat16* xT   = (__hip_bfloat16*)(p + 4 * YB);
    __hip_bfloat16* opre = xT;
    __hip_bfloat16* w1b  = (__hip_bfloat16*)(p + 4 * YB + 802816);
    __hip_bfloat16* wpb  = (__hip_bfloat16*)(p + 4 * YB + 802816 + 98304);

    k_cvt_w<<<dim3(256), 256, 0, stream>>>(w1, wp, w1b, wpb);
    k_cvt_xT<<<dim3(49, 4, 2), 256, 0, stream>>>(x, xT);
    k_gemm<<<dim3(49, 12, 2), 256, 0, stream>>>(w1b, xT, y1, C3);
    k_dw<<<dim3((2 * C3 * SPA) / 256), 256, 0, stream>>>(y1, w2, y2);
    k_attn2<<<dim3(HGT, 2 * NH), 256, 0, stream>>>(y2, rpb0, rpb1, opre);
    k_gemm<<<dim3(49, 4, 2), 256, 0, stream>>>(wpb, opre, out, CCH);
}

// Round 5
// 92.943 us; speedup vs baseline: 2.2150x; 1.2034x over previous
//
#include <hip/hip_runtime.h>
#include <hip/hip_bf16.h>

// Sizes (static per reference)
#define HGT 56
#define WID 56
#define SPA 3136          // 56*56
#define CCH 256
#define C3  768
#define NH  8
#define HD  32
#define YB  2408448       // 768*3136 per-batch y stride
#define ISTR 43008        // 56*768  (reshaped NCHW-flat view: per-i stride)
#define JSTR 768          // per-j stride
#define SCALE_Q 0.17677669529663687f   // 32^-0.5

typedef __attribute__((ext_vector_type(8))) short short8;
typedef __attribute__((ext_vector_type(4))) float f32x4;

static __device__ __forceinline__ unsigned short f2bf_bits(float f) {
    __hip_bfloat16 h = __float2bfloat16(f);
    union { __hip_bfloat16 h; unsigned short u; } cv; cv.h = h; return cv.u;
}
static __device__ __forceinline__ float bf_lo(unsigned u) {
    union { unsigned x; float f; } c; c.x = u << 16; return c.f;
}
static __device__ __forceinline__ float bf_hi(unsigned u) {
    union { unsigned x; float f; } c; c.x = u & 0xffff0000u; return c.f;
}

// ---------------- cvt weights to bf16: w1 (768*256) then wp (256*256)
__global__ __launch_bounds__(256) void k_cvt_w(const float* __restrict__ w1,
                                               const float* __restrict__ wp,
                                               __hip_bfloat16* __restrict__ w1b,
                                               __hip_bfloat16* __restrict__ wpb) {
    int i = (blockIdx.x * 256 + threadIdx.x) * 4;   // 262144 total, exact
    const float* src;
    __hip_bfloat16* dst;
    if (i < 196608) { src = w1 + i; dst = w1b + i; }
    else            { src = wp + (i - 196608); dst = wpb + (i - 196608); }
    float4 v = *(const float4*)src;
    ushort4 u;
    u.x = f2bf_bits(v.x); u.y = f2bf_bits(v.y);
    u.z = f2bf_bits(v.z); u.w = f2bf_bits(v.w);
    *(ushort4*)dst = u;
}

// ---------------- cvt+transpose x: [b][c][s] f32 -> xT [b][s][c] bf16
__global__ __launch_bounds__(256) void k_cvt_xT(const float* __restrict__ x,
                                                __hip_bfloat16* __restrict__ xT) {
    __shared__ __align__(16) __hip_bfloat16 Sl[64][80];   // 160B rows (16B mult)
    const int t = threadIdx.x;
    const int b = blockIdx.z, c0 = blockIdx.y * 64, s0 = blockIdx.x * 64;
    const float* xb = x + (size_t)b * (CCH * SPA);
    const int sq = (t & 15) * 4, cq = (t >> 4) * 4;   // 4x4 micro-tile
    float4 r[4];
#pragma unroll
    for (int rr = 0; rr < 4; ++rr)
        r[rr] = *(const float4*)&xb[(size_t)(c0 + cq + rr) * SPA + s0 + sq];
#pragma unroll
    for (int j = 0; j < 4; ++j) {
        ushort4 u;
        u.x = f2bf_bits(((const float*)&r[0])[j]);
        u.y = f2bf_bits(((const float*)&r[1])[j]);
        u.z = f2bf_bits(((const float*)&r[2])[j]);
        u.w = f2bf_bits(((const float*)&r[3])[j]);
        *(ushort4*)&Sl[sq + j][cq] = u;
    }
    __syncthreads();
    const int srow = t >> 2, cslot = t & 3;
    __hip_bfloat16* dst = &xT[(size_t)b * SPA * CCH + (size_t)(s0 + srow) * CCH + c0];
    short8 v0 = *(const short8*)&Sl[srow][cslot * 8];
    short8 v1 = *(const short8*)&Sl[srow][(cslot + 4) * 8];
    *(short8*)&dst[cslot * 8] = v0;
    *(short8*)&dst[(cslot + 4) * 8] = v1;
}

// ---------------- bf16 MFMA GEMM: C[b][o][s] = sum_c A[o][c] * B[b][s][c]
__global__ __launch_bounds__(256) void k_gemm(const __hip_bfloat16* __restrict__ A,
                                              const __hip_bfloat16* __restrict__ B,
                                              float* __restrict__ C, int M) {
    __shared__ __align__(16) short sA[4096];   // 64 rows x 128B, swizzled
    __shared__ __align__(16) short sB[4096];
    const int t = threadIdx.x;
    const int lane = t & 63, w = t >> 6;
    const int s0 = blockIdx.x * 64, o0 = blockIdx.y * 64, b = blockIdx.z;
    const __hip_bfloat16* Bb = B + (size_t)b * SPA * CCH;

    const int srow = t >> 3;
    const int scol = (t & 7) ^ (srow & 7);
    const char* gA = (const char*)(A  + (size_t)(o0 + srow) * CCH) + scol * 16;
    const char* gB = (const char*)(Bb + (size_t)(s0 + srow) * CCH) + scol * 16;
    char* lA = (char*)sA + w * 1024;
    char* lB = (char*)sB + w * 1024;

    const int wm = w >> 1, wn = w & 1;
    const int lr = lane & 15, kh = lane >> 4;
    const int ar0 = wm * 32 + lr, ar1 = ar0 + 16;
    const int br0 = wn * 32 + lr, br1 = br0 + 16;

    f32x4 acc[2][2] = {};
    for (int kt = 0; kt < 4; ++kt) {
        __builtin_amdgcn_global_load_lds(
            (const __attribute__((address_space(1))) void*)(gA + kt * 128),
            (__attribute__((address_space(3))) void*)lA, 16, 0, 0);
        __builtin_amdgcn_global_load_lds(
            (const __attribute__((address_space(1))) void*)(gA + 16384 + kt * 128),
            (__attribute__((address_space(3))) void*)(lA + 4096), 16, 0, 0);
        __builtin_amdgcn_global_load_lds(
            (const __attribute__((address_space(1))) void*)(gB + kt * 128),
            (__attribute__((address_space(3))) void*)lB, 16, 0, 0);
        __builtin_amdgcn_global_load_lds(
            (const __attribute__((address_space(1))) void*)(gB + 16384 + kt * 128),
            (__attribute__((address_space(3))) void*)(lB + 4096), 16, 0, 0);
        __syncthreads();
#pragma unroll
        for (int kk = 0; kk < 2; ++kk) {
            const int kg = (kk << 2) | kh;
            short8 a0 = *(const short8*)&sA[(ar0 * 128 + ((kg ^ (ar0 & 7)) << 4)) >> 1];
            short8 a1 = *(const short8*)&sA[(ar1 * 128 + ((kg ^ (ar1 & 7)) << 4)) >> 1];
            short8 b0 = *(const short8*)&sB[(br0 * 128 + ((kg ^ (br0 & 7)) << 4)) >> 1];
            short8 b1 = *(const short8*)&sB[(br1 * 128 + ((kg ^ (br1 & 7)) << 4)) >> 1];
            acc[0][0] = __builtin_amdgcn_mfma_f32_16x16x32_bf16(a0, b0, acc[0][0], 0, 0, 0);
            acc[0][1] = __builtin_amdgcn_mfma_f32_16x16x32_bf16(a0, b1, acc[0][1], 0, 0, 0);
            acc[1][0] = __builtin_amdgcn_mfma_f32_16x16x32_bf16(a1, b0, acc[1][0], 0, 0, 0);
            acc[1][1] = __builtin_amdgcn_mfma_f32_16x16x32_bf16(a1, b1, acc[1][1], 0, 0, 0);
        }
        __syncthreads();
    }
    float* Cb = C + (size_t)b * M * SPA;
#pragma unroll
    for (int mi = 0; mi < 2; ++mi)
#pragma unroll
        for (int ni = 0; ni < 2; ++ni) {
            const int r0 = o0 + wm * 32 + mi * 16 + kh * 4;
            const int cc = s0 + wn * 32 + ni * 16 + lr;
#pragma unroll
            for (int q = 0; q < 4; ++q)
                Cb[(size_t)(r0 + q) * SPA + cc] = acc[mi][ni][q];
        }
}

// ---------------- K2: depthwise 3x3 SAME (cross-correlation, zero pad)
__global__ __launch_bounds__(256) void k_dw(const float* __restrict__ y1,
                                            const float* __restrict__ w2,
                                            float* __restrict__ y2) {
    int idx = blockIdx.x * 256 + threadIdx.x;
    int s = idx % SPA;
    int bc = idx / SPA;
    int ch = bc % C3;
    int h = s / WID, w = s % WID;
    const float* in = y1 + (size_t)bc * SPA;
    const float* wt = w2 + ch * 9;
    float acc = 0.f;
#pragma unroll
    for (int dh = -1; dh <= 1; ++dh) {
        int hh = h + dh;
        if (hh < 0 || hh >= HGT) continue;
#pragma unroll
        for (int dw = -1; dw <= 1; ++dw) {
            int ww = w + dw;
            if (ww < 0 || ww >= WID) continue;
            acc += wt[(dh + 1) * 3 + (dw + 1)] * in[hh * WID + ww];
        }
    }
    y2[idx] = acc;
}

// ---------------- K3 v3: per-(half-row) blocks; bf16 K in LDS; no-max softmax.
// Block: (half, i, b*8+head). 4 waves x 7 j-pixels. 35 staged k-cols/half.
template<int D>
__device__ __forceinline__ void attn_body(short* __restrict__ KlB,
                                          float* __restrict__ biasl,
                                          float (*__restrict__ wsm)[64],
                                          int* __restrict__ voff,
                                          const float* __restrict__ y2,
                                          const float* __restrict__ rpb,
                                          __hip_bfloat16* __restrict__ opre,
                                          int b, int head, int i, int half_, int hsub) {
    const int tid = threadIdx.x;
    const int lane = tid & 63, wid = tid >> 6;
    const int cmin = half_ ? 21 : 0;

    int wsi, pbi;
    if (D == 1) {
        wsi = (i < 3) ? 0 : ((i > 52) ? 49 : i - 3);
        pbi = (i < 3) ? 6 - i : ((i > 52) ? 55 - i : 3);
    } else {
        wsi = (i < 6) ? (i & 1) : ((i >= 50) ? 42 + (i & 1) : i - 6);
        pbi = (i < 6) ? 6 - (i >> 1) : ((i >= 50) ? (55 - i) >> 1 : 3);
    }

    const float* ybase = y2 + (size_t)b * YB + head * HD;

    // ---- stage K (bf16) : 35 cols x 7 u-rows x 32 d; row stride 40 shorts (80B).
    // D=2 parity-split col remap keeps QK ds_read_b128 bank-spread.
    const float* kbase = ybase + CCH + wsi * ISTR + cmin * JSTR;
    for (int f = tid; f < 1960; f += 256) {      // 35*7*8 float4-groups
        int col = f / 56;
        int rem = f - col * 56;
        int u = rem >> 3;
        int r = rem & 7;
        float4 s = *((const float4*)(kbase + u * (D * ISTR) + col * JSTR) + r);
        ushort4 o;
        o.x = f2bf_bits(s.x); o.y = f2bf_bits(s.y);
        o.z = f2bf_bits(s.z); o.w = f2bf_bits(s.w);
        const int colS = (D == 1) ? col : ((col >> 1) + (col & 1) * 18);
        *(ushort4*)&KlB[(colS * 7 + u) * 40 + r * 4] = o;
    }
    if (tid < 169) biasl[tid] = rpb[hsub * 169 + tid];
    if (tid < 50) {
        int uu = tid / 7, vv = tid - uu * 7;
        voff[tid] = (tid < 49) ? D * (uu * ISTR + vv * JSTR) : 0;
    }
    __syncthreads();

    int u = lane / 7, v = lane - u * 7;
    const bool act = lane < 49;
    if (!act) { u = 0; v = 0; }
    const int bconst = u * 13 + v + pbi * 13;
    const int d = lane & 31, half = lane >> 5;
    const float* vbS = ybase + 2 * CCH + wsi * ISTR;

    for (int jj = 0; jj < 7; ++jj) {
        const int j = half_ * 28 + wid * 7 + jj;
        int wsj, pbj;
        if (D == 1) {
            wsj = (j < 3) ? 0 : ((j > 52) ? 49 : j - 3);
            pbj = (j < 3) ? 6 - j : ((j > 52) ? 55 - j : 3);
        } else {
            wsj = (j < 6) ? (j & 1) : ((j >= 50) ? 42 + (j & 1) : j - 6);
            pbj = (j < 6) ? 6 - (j >> 1) : ((j >= 50) ? (55 - j) >> 1 : 3);
        }

        // q: uniform 32 floats
        float q[32];
        const float4* qp = (const float4*)(ybase + i * ISTR + j * JSTR);
#pragma unroll
        for (int r = 0; r < 8; ++r) {
            float4 tq = qp[r];
            q[r * 4 + 0] = tq.x; q[r * 4 + 1] = tq.y;
            q[r * 4 + 2] = tq.z; q[r * 4 + 3] = tq.w;
        }

        // QK from bf16 LDS
        int rrl;
        const int kcol0 = wsj - cmin;
        if (D == 1) rrl = (kcol0 + v) * 7 + u;
        else {
            const int kc = kcol0 + 2 * v;
            rrl = ((kc >> 1) + (kc & 1) * 18) * 7 + u;
        }
        const short* kp = &KlB[rrl * 40];
        float acc = 0.f;
#pragma unroll
        for (int s = 0; s < 4; ++s) {
            short8 kk = *(const short8*)(kp + s * 8);
            const unsigned* ku = (const unsigned*)&kk;
#pragma unroll
            for (int e = 0; e < 4; ++e) {
                acc += q[s * 8 + 2 * e]     * bf_lo(ku[e]);
                acc += q[s * 8 + 2 * e + 1] * bf_hi(ku[e]);
            }
        }

        // no-max softmax (logits ~N(0,1): exp safe in f32; identical math)
        float e = act ? __expf(acc * SCALE_Q + biasl[bconst + pbj]) : 0.f;
        float ssum = e;
#pragma unroll
        for (int off = 32; off; off >>= 1) ssum += __shfl_xor(ssum, off);
        const float wgt = e * __frcp_rn(ssum);
        wsm[wid][lane] = wgt;   // same-wave LDS: in-order

        // PV: 25 steps/half; slot 49 is weight-0/offset-0 pad
        const unsigned pixoff = (unsigned)(wsj * JSTR + d);
        float oacc = 0.f;
#pragma unroll
        for (int tt = 0; tt < 25; ++tt) {
            const int p = half * 25 + tt;
            const float wv = wsm[wid][p];
            const unsigned off = pixoff + (unsigned)voff[p];
            oacc += wv * vbS[off];
        }
        oacc += __shfl_xor(oacc, 32);
        if (half == 0)
            opre[(size_t)b * (SPA * CCH) + (size_t)(i * WID + j) * CCH + head * HD + d] =
                __float2bfloat16(oacc);
    }
}

__global__ __launch_bounds__(256) void k_attn3(const float* __restrict__ y2,
                                               const float* __restrict__ rpb0,
                                               const float* __restrict__ rpb1,
                                               __hip_bfloat16* __restrict__ opre) {
    __shared__ __align__(16) short KlB[9800];   // 35*7*40 shorts = 19600B
    __shared__ float biasl[169];
    __shared__ float wsm[4][64];
    __shared__ int   voff[52];
    const int half_ = blockIdx.x;
    const int i = blockIdx.y;
    const int bh = blockIdx.z;
    const int b = bh >> 3, head = bh & 7;
    if (head < 4)
        attn_body<1>(KlB, biasl, wsm, voff, y2, rpb0, opre, b, head, i, half_, head);
    else
        attn_body<2>(KlB, biasl, wsm, voff, y2, rpb1, opre, b, head, i, half_, head - 4);
}

extern "C" void kernel_launch(void* const* d_in, const int* in_sizes, int n_in,
                              void* d_out, int out_size, void* d_ws, size_t ws_size,
                              hipStream_t stream) {
    const float* x    = (const float*)d_in[0];
    const float* w1   = (const float*)d_in[1];
    const float* w2   = (const float*)d_in[2];
    const float* rpb0 = (const float*)d_in[3];
    const float* rpb1 = (const float*)d_in[4];
    const float* wp   = (const float*)d_in[5];
    float* out = (float*)d_out;

    float* p = (float*)d_ws;
    float* y1 = p;                       // [2][768][3136] f32
    float* y2 = p + 2 * YB;              // [2][768][3136] f32
    __hip_bfloat16* xT   = (__hip_bfloat16*)(p + 4 * YB);
    __hip_bfloat16* opre = xT;           // disjoint lifetimes
    __hip_bfloat16* w1b  = (__hip_bfloat16*)(p + 4 * YB + 802816);
    __hip_bfloat16* wpb  = (__hip_bfloat16*)(p + 4 * YB + 802816 + 98304);

    k_cvt_w<<<dim3(256), 256, 0, stream>>>(w1, wp, w1b, wpb);
    k_cvt_xT<<<dim3(49, 4, 2), 256, 0, stream>>>(x, xT);
    k_gemm<<<dim3(49, 12, 2), 256, 0, stream>>>(w1b, xT, y1, C3);
    k_dw<<<dim3((2 * C3 * SPA) / 256), 256, 0, stream>>>(y1, w2, y2);
    k_attn3<<<dim3(2, HGT, 2 * NH), 256, 0, stream>>>(y2, rpb0, rpb1, opre);
    k_gemm<<<dim3(49, 4, 2), 256, 0, stream>>>(wpb, opre, out, CCH);
}

// Round 6
// 77.640 us; speedup vs baseline: 2.6517x; 1.1971x over previous
//
#include <hip/hip_runtime.h>
#include <hip/hip_bf16.h>

// Sizes (static per reference)
#define HGT 56
#define WID 56
#define SPA 3136          // 56*56
#define CCH 256
#define C3  768
#define NH  8
#define HD  32
#define YB  2408448       // 768*3136 per-batch y stride
#define ISTR 43008        // 56*768  (reshaped NCHW-flat view: per-i stride)
#define JSTR 768          // per-j stride
#define SCALE_Q 0.17677669529663687f   // 32^-0.5

typedef __attribute__((ext_vector_type(8))) short short8;
typedef __attribute__((ext_vector_type(4))) float f32x4;

static __device__ __forceinline__ unsigned short f2bf_bits(float f) {
    __hip_bfloat16 h = __float2bfloat16(f);
    union { __hip_bfloat16 h; unsigned short u; } cv; cv.h = h; return cv.u;
}
static __device__ __forceinline__ float bf_lo(unsigned u) {
    union { unsigned x; float f; } c; c.x = u << 16; return c.f;
}
static __device__ __forceinline__ float bf_hi(unsigned u) {
    union { unsigned x; float f; } c; c.x = u & 0xffff0000u; return c.f;
}

// ---------------- cvt weights to bf16: w1 (768*256) then wp (256*256)
__global__ __launch_bounds__(256) void k_cvt_w(const float* __restrict__ w1,
                                               const float* __restrict__ wp,
                                               __hip_bfloat16* __restrict__ w1b,
                                               __hip_bfloat16* __restrict__ wpb) {
    int i = (blockIdx.x * 256 + threadIdx.x) * 4;   // 262144 total, exact
    const float* src;
    __hip_bfloat16* dst;
    if (i < 196608) { src = w1 + i; dst = w1b + i; }
    else            { src = wp + (i - 196608); dst = wpb + (i - 196608); }
    float4 v = *(const float4*)src;
    ushort4 u;
    u.x = f2bf_bits(v.x); u.y = f2bf_bits(v.y);
    u.z = f2bf_bits(v.z); u.w = f2bf_bits(v.w);
    *(ushort4*)dst = u;
}

// ---------------- cvt+transpose x: [b][c][s] f32 -> xT [b][s][c] bf16
__global__ __launch_bounds__(256) void k_cvt_xT(const float* __restrict__ x,
                                                __hip_bfloat16* __restrict__ xT) {
    __shared__ __align__(16) __hip_bfloat16 Sl[64][80];   // 160B rows (16B mult)
    const int t = threadIdx.x;
    const int b = blockIdx.z, c0 = blockIdx.y * 64, s0 = blockIdx.x * 64;
    const float* xb = x + (size_t)b * (CCH * SPA);
    const int sq = (t & 15) * 4, cq = (t >> 4) * 4;   // 4x4 micro-tile
    float4 r[4];
#pragma unroll
    for (int rr = 0; rr < 4; ++rr)
        r[rr] = *(const float4*)&xb[(size_t)(c0 + cq + rr) * SPA + s0 + sq];
#pragma unroll
    for (int j = 0; j < 4; ++j) {
        ushort4 u;
        u.x = f2bf_bits(((const float*)&r[0])[j]);
        u.y = f2bf_bits(((const float*)&r[1])[j]);
        u.z = f2bf_bits(((const float*)&r[2])[j]);
        u.w = f2bf_bits(((const float*)&r[3])[j]);
        *(ushort4*)&Sl[sq + j][cq] = u;
    }
    __syncthreads();
    const int srow = t >> 2, cslot = t & 3;
    __hip_bfloat16* dst = &xT[(size_t)b * SPA * CCH + (size_t)(s0 + srow) * CCH + c0];
    short8 v0 = *(const short8*)&Sl[srow][cslot * 8];
    short8 v1 = *(const short8*)&Sl[srow][(cslot + 4) * 8];
    *(short8*)&dst[cslot * 8] = v0;
    *(short8*)&dst[(cslot + 4) * 8] = v1;
}

// ---------------- bf16 MFMA GEMM: C[b][o][s] = sum_c A[o][c] * B[b][s][c]
__global__ __launch_bounds__(256) void k_gemm(const __hip_bfloat16* __restrict__ A,
                                              const __hip_bfloat16* __restrict__ B,
                                              float* __restrict__ C, int M) {
    __shared__ __align__(16) short sA[4096];   // 64 rows x 128B, swizzled
    __shared__ __align__(16) short sB[4096];
    const int t = threadIdx.x;
    const int lane = t & 63, w = t >> 6;
    const int s0 = blockIdx.x * 64, o0 = blockIdx.y * 64, b = blockIdx.z;
    const __hip_bfloat16* Bb = B + (size_t)b * SPA * CCH;

    const int srow = t >> 3;
    const int scol = (t & 7) ^ (srow & 7);
    const char* gA = (const char*)(A  + (size_t)(o0 + srow) * CCH) + scol * 16;
    const char* gB = (const char*)(Bb + (size_t)(s0 + srow) * CCH) + scol * 16;
    char* lA = (char*)sA + w * 1024;
    char* lB = (char*)sB + w * 1024;

    const int wm = w >> 1, wn = w & 1;
    const int lr = lane & 15, kh = lane >> 4;
    const int ar0 = wm * 32 + lr, ar1 = ar0 + 16;
    const int br0 = wn * 32 + lr, br1 = br0 + 16;

    f32x4 acc[2][2] = {};
    for (int kt = 0; kt < 4; ++kt) {
        __builtin_amdgcn_global_load_lds(
            (const __attribute__((address_space(1))) void*)(gA + kt * 128),
            (__attribute__((address_space(3))) void*)lA, 16, 0, 0);
        __builtin_amdgcn_global_load_lds(
            (const __attribute__((address_space(1))) void*)(gA + 16384 + kt * 128),
            (__attribute__((address_space(3))) void*)(lA + 4096), 16, 0, 0);
        __builtin_amdgcn_global_load_lds(
            (const __attribute__((address_space(1))) void*)(gB + kt * 128),
            (__attribute__((address_space(3))) void*)lB, 16, 0, 0);
        __builtin_amdgcn_global_load_lds(
            (const __attribute__((address_space(1))) void*)(gB + 16384 + kt * 128),
            (__attribute__((address_space(3))) void*)(lB + 4096), 16, 0, 0);
        __syncthreads();
#pragma unroll
        for (int kk = 0; kk < 2; ++kk) {
            const int kg = (kk << 2) | kh;
            short8 a0 = *(const short8*)&sA[(ar0 * 128 + ((kg ^ (ar0 & 7)) << 4)) >> 1];
            short8 a1 = *(const short8*)&sA[(ar1 * 128 + ((kg ^ (ar1 & 7)) << 4)) >> 1];
            short8 b0 = *(const short8*)&sB[(br0 * 128 + ((kg ^ (br0 & 7)) << 4)) >> 1];
            short8 b1 = *(const short8*)&sB[(br1 * 128 + ((kg ^ (br1 & 7)) << 4)) >> 1];
            acc[0][0] = __builtin_amdgcn_mfma_f32_16x16x32_bf16(a0, b0, acc[0][0], 0, 0, 0);
            acc[0][1] = __builtin_amdgcn_mfma_f32_16x16x32_bf16(a0, b1, acc[0][1], 0, 0, 0);
            acc[1][0] = __builtin_amdgcn_mfma_f32_16x16x32_bf16(a1, b0, acc[1][0], 0, 0, 0);
            acc[1][1] = __builtin_amdgcn_mfma_f32_16x16x32_bf16(a1, b1, acc[1][1], 0, 0, 0);
        }
        __syncthreads();
    }
    float* Cb = C + (size_t)b * M * SPA;
#pragma unroll
    for (int mi = 0; mi < 2; ++mi)
#pragma unroll
        for (int ni = 0; ni < 2; ++ni) {
            const int r0 = o0 + wm * 32 + mi * 16 + kh * 4;
            const int cc = s0 + wn * 32 + ni * 16 + lr;
#pragma unroll
            for (int q = 0; q < 4; ++q)
                Cb[(size_t)(r0 + q) * SPA + cc] = acc[mi][ni][q];
        }
}

// ---------------- K2: depthwise 3x3 SAME, x4 vectorized along w
__global__ __launch_bounds__(256) void k_dw(const float* __restrict__ y1,
                                            const float* __restrict__ w2,
                                            float* __restrict__ y2) {
    int idx = blockIdx.x * 256 + threadIdx.x;   // 2*768*56*14 = 1204224 (exact)
    int tw = idx % 14;
    int rest = idx / 14;
    int h = rest % HGT;
    int bc = rest / HGT;          // b*768 + ch
    int w0 = tw * 4;
    const float* in = y1 + (size_t)bc * SPA;
    const float* wt = w2 + (bc % C3) * 9;
    float4 acc = {0.f, 0.f, 0.f, 0.f};
#pragma unroll
    for (int dh = -1; dh <= 1; ++dh) {
        int hh = h + dh;
        if (hh < 0 || hh >= HGT) continue;
        const float* rp = in + hh * WID + w0;
        float4 c = *(const float4*)rp;
        float l = (w0 > 0) ? rp[-1] : 0.f;
        float r = (w0 < 52) ? rp[4] : 0.f;
        float wl = wt[(dh + 1) * 3 + 0];
        float wc = wt[(dh + 1) * 3 + 1];
        float wr = wt[(dh + 1) * 3 + 2];
        acc.x += wl * l   + wc * c.x + wr * c.y;
        acc.y += wl * c.x + wc * c.y + wr * c.z;
        acc.z += wl * c.y + wc * c.z + wr * c.w;
        acc.w += wl * c.z + wc * c.w + wr * r;
    }
    *(float4*)(y2 + (size_t)bc * SPA + h * WID + w0) = acc;
}

// ---------------- K3 v4: K+V bf16 in LDS; weight distribution via shuffles;
// PV as 16 d-pairs x 4 quarters x 13 positions from LDS; q double-buffered.
template<int D>
__device__ __forceinline__ void attn_body(short* __restrict__ Kl,
                                          unsigned short* __restrict__ Vl,
                                          float* __restrict__ biasl,
                                          int* __restrict__ cpvt,
                                          const float* __restrict__ y2,
                                          const float* __restrict__ rpb,
                                          __hip_bfloat16* __restrict__ opre,
                                          int b, int head, int i, int half_, int hsub) {
    const int tid = threadIdx.x;
    const int lane = tid & 63, wid = tid >> 6;
    const int cmin = half_ ? 21 : 0;

    int wsi, pbi;
    if (D == 1) {
        wsi = (i < 3) ? 0 : ((i > 52) ? 49 : i - 3);
        pbi = (i < 3) ? 6 - i : ((i > 52) ? 55 - i : 3);
    } else {
        wsi = (i < 6) ? (i & 1) : ((i >= 50) ? 42 + (i & 1) : i - 6);
        pbi = (i < 6) ? 6 - (i >> 1) : ((i >= 50) ? (55 - i) >> 1 : 3);
    }

    const float* ybase = y2 + (size_t)b * YB + head * HD;

    // ---- stage K (bf16, remapped cols, 40-short rows) and V (bf16, linear cols,
    // 36-short rows = 72B: 8B-aligned stores, odd word-stride spreads banks)
    const float* kbase = ybase + CCH     + wsi * ISTR + cmin * JSTR;
    const float* vbase = ybase + 2 * CCH + wsi * ISTR + cmin * JSTR;
    for (int f = tid; f < 1960; f += 256) {      // 35 cols * 7 u * 8 float4
        int col = f / 56;
        int rem = f - col * 56;
        int u = rem >> 3;
        int r = rem & 7;
        const int goff = u * (D * ISTR) + col * JSTR;
        float4 s = *((const float4*)(kbase + goff) + r);
        ushort4 o;
        o.x = f2bf_bits(s.x); o.y = f2bf_bits(s.y);
        o.z = f2bf_bits(s.z); o.w = f2bf_bits(s.w);
        const int colS = (D == 1) ? col : ((col >> 1) + (col & 1) * 18);
        *(ushort4*)&Kl[(colS * 7 + u) * 40 + r * 4] = o;
        float4 sv = *((const float4*)(vbase + goff) + r);
        ushort4 ov;
        ov.x = f2bf_bits(sv.x); ov.y = f2bf_bits(sv.y);
        ov.z = f2bf_bits(sv.z); ov.w = f2bf_bits(sv.w);
        *(ushort4*)&Vl[(col * 7 + u) * 36 + r * 4] = ov;
    }
    if (tid < 169) biasl[tid] = rpb[hsub * 169 + tid];
    if (tid < 52) {
        int uu = tid / 7, vv = tid - uu * 7;
        cpvt[tid] = (tid < 49) ? (D * vv * 7 + uu) * 18 : 0;   // word offsets
    }
    __syncthreads();

    int u = lane / 7, v = lane - u * 7;
    const bool act = lane < 49;
    if (!act) { u = 0; v = 0; }
    const int bconst = u * 13 + v + pbi * 13;
    const int qt = lane >> 4, dp = lane & 15;
    const unsigned* Vw = (const unsigned*)Vl;

    int cpw[13];
#pragma unroll
    for (int t = 0; t < 13; ++t) cpw[t] = cpvt[qt * 13 + t];

    const int j0 = half_ * 28 + wid * 7;

    float qA[32], qB[32];
#define LOADQ(dst, jx)                                                     \
    {                                                                      \
        const float4* qp = (const float4*)(ybase + i * ISTR + (jx) * JSTR);\
        _Pragma("unroll")                                                  \
        for (int r = 0; r < 8; ++r) {                                      \
            float4 tq = qp[r];                                             \
            dst[4 * r + 0] = tq.x; dst[4 * r + 1] = tq.y;                  \
            dst[4 * r + 2] = tq.z; dst[4 * r + 3] = tq.w;                  \
        }                                                                  \
    }

    auto body = [&](const float (&q)[32], float (&qn)[32], int jj, bool pre) {
        const int j = j0 + jj;
        int wsj, pbj;
        if (D == 1) {
            wsj = (j < 3) ? 0 : ((j > 52) ? 49 : j - 3);
            pbj = (j < 3) ? 6 - j : ((j > 52) ? 55 - j : 3);
        } else {
            wsj = (j < 6) ? (j & 1) : ((j >= 50) ? 42 + (j & 1) : j - 6);
            pbj = (j < 6) ? 6 - (j >> 1) : ((j >= 50) ? (55 - j) >> 1 : 3);
        }
        if (pre) LOADQ(qn, j + 1);
        const int kcol0 = wsj - cmin;

        // QK from bf16 LDS
        int rrl;
        if (D == 1) rrl = (kcol0 + v) * 7 + u;
        else {
            const int kc = kcol0 + 2 * v;
            rrl = ((kc >> 1) + (kc & 1) * 18) * 7 + u;
        }
        const short* kp = &Kl[rrl * 40];
        float acc = 0.f;
#pragma unroll
        for (int s = 0; s < 4; ++s) {
            short8 kk = *(const short8*)(kp + s * 8);
            const unsigned* ku = (const unsigned*)&kk;
#pragma unroll
            for (int e = 0; e < 4; ++e) {
                acc += q[s * 8 + 2 * e]     * bf_lo(ku[e]);
                acc += q[s * 8 + 2 * e + 1] * bf_hi(ku[e]);
            }
        }

        // no-max softmax (logits ~N(0,1): exp exact-safe in f32)
        float e = act ? __expf(acc * SCALE_Q + biasl[bconst + pbj]) : 0.f;
        float ssum = e;
#pragma unroll
        for (int off = 32; off; off >>= 1) ssum += __shfl_xor(ssum, off);
        const float wgt = e * __frcp_rn(ssum);

        // PV from LDS: quarter qt covers positions qt*13 .. qt*13+12
        const int vbw = kcol0 * 126 + dp;    // word base (126 = 7*18)
        float o0 = 0.f, o1 = 0.f;
#pragma unroll
        for (int t = 0; t < 13; ++t) {
            const float wv = __shfl(wgt, qt * 13 + t);
            const unsigned vw = Vw[vbw + cpw[t]];
            o0 += wv * bf_lo(vw);
            o1 += wv * bf_hi(vw);
        }
        o0 += __shfl_xor(o0, 16); o0 += __shfl_xor(o0, 32);
        o1 += __shfl_xor(o1, 16); o1 += __shfl_xor(o1, 32);
        if (lane < 16) {
            union { ushort2 s; unsigned w; } pk;
            pk.s.x = f2bf_bits(o0);
            pk.s.y = f2bf_bits(o1);
            *(unsigned*)&opre[(size_t)b * (SPA * CCH) +
                              (size_t)(i * WID + j) * CCH + head * HD + dp * 2] = pk.w;
        }
    };

    LOADQ(qA, j0);
    body(qA, qB, 0, true);
    body(qB, qA, 1, true);
    body(qA, qB, 2, true);
    body(qB, qA, 3, true);
    body(qA, qB, 4, true);
    body(qB, qA, 5, true);
    body(qA, qB, 6, false);
#undef LOADQ
}

__global__ __launch_bounds__(256) void k_attn4(const float* __restrict__ y2,
                                               const float* __restrict__ rpb0,
                                               const float* __restrict__ rpb1,
                                               __hip_bfloat16* __restrict__ opre) {
    __shared__ __align__(16) short Kl[9800];            // 35*7 rows x 40 shorts
    __shared__ __align__(16) unsigned short Vl[8820];   // 35*7 rows x 36 shorts
    __shared__ float biasl[169];
    __shared__ int   cpvt[52];
    const int half_ = blockIdx.x;
    const int i = blockIdx.y;
    const int bh = blockIdx.z;
    const int b = bh >> 3, head = bh & 7;
    if (head < 4)
        attn_body<1>(Kl, Vl, biasl, cpvt, y2, rpb0, opre, b, head, i, half_, head);
    else
        attn_body<2>(Kl, Vl, biasl, cpvt, y2, rpb1, opre, b, head, i, half_, head - 4);
}

extern "C" void kernel_launch(void* const* d_in, const int* in_sizes, int n_in,
                              void* d_out, int out_size, void* d_ws, size_t ws_size,
                              hipStream_t stream) {
    const float* x    = (const float*)d_in[0];
    const float* w1   = (const float*)d_in[1];
    const float* w2   = (const float*)d_in[2];
    const float* rpb0 = (const float*)d_in[3];
    const float* rpb1 = (const float*)d_in[4];
    const float* wp   = (const float*)d_in[5];
    float* out = (float*)d_out;

    float* p = (float*)d_ws;
    float* y1 = p;                       // [2][768][3136] f32
    float* y2 = p + 2 * YB;              // [2][768][3136] f32
    __hip_bfloat16* xT   = (__hip_bfloat16*)(p + 4 * YB);
    __hip_bfloat16* opre = xT;           // disjoint lifetimes
    __hip_bfloat16* w1b  = (__hip_bfloat16*)(p + 4 * YB + 802816);
    __hip_bfloat16* wpb  = (__hip_bfloat16*)(p + 4 * YB + 802816 + 98304);

    k_cvt_w<<<dim3(256), 256, 0, stream>>>(w1, wp, w1b, wpb);
    k_cvt_xT<<<dim3(49, 4, 2), 256, 0, stream>>>(x, xT);
    k_gemm<<<dim3(49, 12, 2), 256, 0, stream>>>(w1b, xT, y1, C3);
    k_dw<<<dim3(4704), 256, 0, stream>>>(y1, w2, y2);
    k_attn4<<<dim3(2, HGT, 2 * NH), 256, 0, stream>>>(y2, rpb0, rpb1, opre);
    k_gemm<<<dim3(49, 4, 2), 256, 0, stream>>>(wpb, opre, out, CCH);
}

// Round 7
// 66.090 us; speedup vs baseline: 3.1150x; 1.1747x over previous
//
#include <hip/hip_runtime.h>
#include <hip/hip_bf16.h>

// Sizes (static per reference)
#define HGT 56
#define WID 56
#define SPA 3136          // 56*56
#define CCH 256
#define C3  768
#define NH  8
#define HD  32
#define YB  2408448       // 768*3136 per-batch y stride
#define ISTR 43008        // 56*768  (reshaped NCHW-flat view: per-i stride)
#define JSTR 768          // per-j stride
#define SCALE_Q 0.17677669529663687f   // 32^-0.5

typedef __attribute__((ext_vector_type(8))) short short8;
typedef __attribute__((ext_vector_type(4))) float f32x4;

static __device__ __forceinline__ unsigned short f2bf_bits(float f) {
    __hip_bfloat16 h = __float2bfloat16(f);
    union { __hip_bfloat16 h; unsigned short u; } cv; cv.h = h; return cv.u;
}
static __device__ __forceinline__ float bf_lo(unsigned u) {
    union { unsigned x; float f; } c; c.x = u << 16; return c.f;
}
static __device__ __forceinline__ float bf_hi(unsigned u) {
    union { unsigned x; float f; } c; c.x = u & 0xffff0000u; return c.f;
}

// ---------------- cvt: xT (z<2) + weights (z==2) in one dispatch
__global__ __launch_bounds__(256) void k_cvt(const float* __restrict__ x,
                                             const float* __restrict__ w1,
                                             const float* __restrict__ wp,
                                             __hip_bfloat16* __restrict__ xT,
                                             __hip_bfloat16* __restrict__ w1b,
                                             __hip_bfloat16* __restrict__ wpb) {
    __shared__ __align__(16) __hip_bfloat16 Sl[64][80];   // 160B rows
    const int t = threadIdx.x;
    const int z = blockIdx.z;
    if (z == 2) {   // weights: w1 (196608) then wp (65536), grid-stride x4
        const int gid = (blockIdx.y * 49 + blockIdx.x) * 256 + t;
        for (int i = gid * 4; i < 262144; i += 200704) {
            const float* src;
            __hip_bfloat16* dst;
            if (i < 196608) { src = w1 + i; dst = w1b + i; }
            else            { src = wp + (i - 196608); dst = wpb + (i - 196608); }
            float4 v = *(const float4*)src;
            ushort4 u;
            u.x = f2bf_bits(v.x); u.y = f2bf_bits(v.y);
            u.z = f2bf_bits(v.z); u.w = f2bf_bits(v.w);
            *(ushort4*)dst = u;
        }
        return;
    }
    const int b = z, c0 = blockIdx.y * 64, s0 = blockIdx.x * 64;
    const float* xb = x + (size_t)b * (CCH * SPA);
    const int sq = (t & 15) * 4, cq = (t >> 4) * 4;   // 4x4 micro-tile
    float4 r[4];
#pragma unroll
    for (int rr = 0; rr < 4; ++rr)
        r[rr] = *(const float4*)&xb[(size_t)(c0 + cq + rr) * SPA + s0 + sq];
#pragma unroll
    for (int j = 0; j < 4; ++j) {
        ushort4 u;
        u.x = f2bf_bits(((const float*)&r[0])[j]);
        u.y = f2bf_bits(((const float*)&r[1])[j]);
        u.z = f2bf_bits(((const float*)&r[2])[j]);
        u.w = f2bf_bits(((const float*)&r[3])[j]);
        *(ushort4*)&Sl[sq + j][cq] = u;
    }
    __syncthreads();
    const int srow = t >> 2, cslot = t & 3;
    __hip_bfloat16* dst = &xT[(size_t)b * SPA * CCH + (size_t)(s0 + srow) * CCH + c0];
    short8 v0 = *(const short8*)&Sl[srow][cslot * 8];
    short8 v1 = *(const short8*)&Sl[srow][(cslot + 4) * 8];
    *(short8*)&dst[cslot * 8] = v0;
    *(short8*)&dst[(cslot + 4) * 8] = v1;
}

// ---------------- bf16 MFMA GEMM: C[b][o][s] = sum_c A[o][c] * B[b][s][c]
__global__ __launch_bounds__(256) void k_gemm(const __hip_bfloat16* __restrict__ A,
                                              const __hip_bfloat16* __restrict__ B,
                                              float* __restrict__ C, int M) {
    __shared__ __align__(16) short sA[4096];   // 64 rows x 128B, swizzled
    __shared__ __align__(16) short sB[4096];
    const int t = threadIdx.x;
    const int lane = t & 63, w = t >> 6;
    const int s0 = blockIdx.x * 64, o0 = blockIdx.y * 64, b = blockIdx.z;
    const __hip_bfloat16* Bb = B + (size_t)b * SPA * CCH;

    const int srow = t >> 3;
    const int scol = (t & 7) ^ (srow & 7);
    const char* gA = (const char*)(A  + (size_t)(o0 + srow) * CCH) + scol * 16;
    const char* gB = (const char*)(Bb + (size_t)(s0 + srow) * CCH) + scol * 16;
    char* lA = (char*)sA + w * 1024;
    char* lB = (char*)sB + w * 1024;

    const int wm = w >> 1, wn = w & 1;
    const int lr = lane & 15, kh = lane >> 4;
    const int ar0 = wm * 32 + lr, ar1 = ar0 + 16;
    const int br0 = wn * 32 + lr, br1 = br0 + 16;

    f32x4 acc[2][2] = {};
    for (int kt = 0; kt < 4; ++kt) {
        __builtin_amdgcn_global_load_lds(
            (const __attribute__((address_space(1))) void*)(gA + kt * 128),
            (__attribute__((address_space(3))) void*)lA, 16, 0, 0);
        __builtin_amdgcn_global_load_lds(
            (const __attribute__((address_space(1))) void*)(gA + 16384 + kt * 128),
            (__attribute__((address_space(3))) void*)(lA + 4096), 16, 0, 0);
        __builtin_amdgcn_global_load_lds(
            (const __attribute__((address_space(1))) void*)(gB + kt * 128),
            (__attribute__((address_space(3))) void*)lB, 16, 0, 0);
        __builtin_amdgcn_global_load_lds(
            (const __attribute__((address_space(1))) void*)(gB + 16384 + kt * 128),
            (__attribute__((address_space(3))) void*)(lB + 4096), 16, 0, 0);
        __syncthreads();
#pragma unroll
        for (int kk = 0; kk < 2; ++kk) {
            const int kg = (kk << 2) | kh;
            short8 a0 = *(const short8*)&sA[(ar0 * 128 + ((kg ^ (ar0 & 7)) << 4)) >> 1];
            short8 a1 = *(const short8*)&sA[(ar1 * 128 + ((kg ^ (ar1 & 7)) << 4)) >> 1];
            short8 b0 = *(const short8*)&sB[(br0 * 128 + ((kg ^ (br0 & 7)) << 4)) >> 1];
            short8 b1 = *(const short8*)&sB[(br1 * 128 + ((kg ^ (br1 & 7)) << 4)) >> 1];
            acc[0][0] = __builtin_amdgcn_mfma_f32_16x16x32_bf16(a0, b0, acc[0][0], 0, 0, 0);
            acc[0][1] = __builtin_amdgcn_mfma_f32_16x16x32_bf16(a0, b1, acc[0][1], 0, 0, 0);
            acc[1][0] = __builtin_amdgcn_mfma_f32_16x16x32_bf16(a1, b0, acc[1][0], 0, 0, 0);
            acc[1][1] = __builtin_amdgcn_mfma_f32_16x16x32_bf16(a1, b1, acc[1][1], 0, 0, 0);
        }
        __syncthreads();
    }
    float* Cb = C + (size_t)b * M * SPA;
#pragma unroll
    for (int mi = 0; mi < 2; ++mi)
#pragma unroll
        for (int ni = 0; ni < 2; ++ni) {
            const int r0 = o0 + wm * 32 + mi * 16 + kh * 4;
            const int cc = s0 + wn * 32 + ni * 16 + lr;
#pragma unroll
            for (int q = 0; q < 4; ++q)
                Cb[(size_t)(r0 + q) * SPA + cc] = acc[mi][ni][q];
        }
}

// ---------------- K2: depthwise 3x3 SAME, x4 along w, bf16 output
__global__ __launch_bounds__(256) void k_dw(const float* __restrict__ y1,
                                            const float* __restrict__ w2,
                                            __hip_bfloat16* __restrict__ y2) {
    int idx = blockIdx.x * 256 + threadIdx.x;   // 2*768*56*14 = 1204224 (exact)
    int tw = idx % 14;
    int rest = idx / 14;
    int h = rest % HGT;
    int bc = rest / HGT;          // b*768 + ch
    int w0 = tw * 4;
    const float* in = y1 + (size_t)bc * SPA;
    const float* wt = w2 + (bc % C3) * 9;
    float4 acc = {0.f, 0.f, 0.f, 0.f};
#pragma unroll
    for (int dh = -1; dh <= 1; ++dh) {
        int hh = h + dh;
        if (hh < 0 || hh >= HGT) continue;
        const float* rp = in + hh * WID + w0;
        float4 c = *(const float4*)rp;
        float l = (w0 > 0) ? rp[-1] : 0.f;
        float r = (w0 < 52) ? rp[4] : 0.f;
        float wl = wt[(dh + 1) * 3 + 0];
        float wc = wt[(dh + 1) * 3 + 1];
        float wr = wt[(dh + 1) * 3 + 2];
        acc.x += wl * l   + wc * c.x + wr * c.y;
        acc.y += wl * c.x + wc * c.y + wr * c.z;
        acc.z += wl * c.y + wc * c.z + wr * c.w;
        acc.w += wl * c.z + wc * c.w + wr * r;
    }
    ushort4 o;
    o.x = f2bf_bits(acc.x); o.y = f2bf_bits(acc.y);
    o.z = f2bf_bits(acc.z); o.w = f2bf_bits(acc.w);
    *(ushort4*)(y2 + (size_t)bc * SPA + h * WID + w0) = o;
}

// ---------------- K3 v5: y2 bf16; K+V staged as pure short8 copies;
// PV 16 d-pairs x 4 quarters x 13 positions; q double-buffered.
template<int D>
__device__ __forceinline__ void attn_body(short* __restrict__ Kl,
                                          short* __restrict__ Vl,
                                          float* __restrict__ biasl,
                                          int* __restrict__ cpvt,
                                          const __hip_bfloat16* __restrict__ y2,
                                          const float* __restrict__ rpb,
                                          __hip_bfloat16* __restrict__ opre,
                                          int b, int head, int i, int half_, int hsub) {
    const int tid = threadIdx.x;
    const int lane = tid & 63, wid = tid >> 6;
    const int cmin = half_ ? 21 : 0;

    int wsi, pbi;
    if (D == 1) {
        wsi = (i < 3) ? 0 : ((i > 52) ? 49 : i - 3);
        pbi = (i < 3) ? 6 - i : ((i > 52) ? 55 - i : 3);
    } else {
        wsi = (i < 6) ? (i & 1) : ((i >= 50) ? 42 + (i & 1) : i - 6);
        pbi = (i < 6) ? 6 - (i >> 1) : ((i >= 50) ? (55 - i) >> 1 : 3);
    }

    const __hip_bfloat16* ybase = y2 + (size_t)b * YB + head * HD;

    // ---- stage K (remapped cols) and V (linear cols); rows = 40 shorts (80B)
    const __hip_bfloat16* kbase = ybase + CCH     + wsi * ISTR + cmin * JSTR;
    const __hip_bfloat16* vbase = ybase + 2 * CCH + wsi * ISTR + cmin * JSTR;
    for (int f = tid; f < 1960; f += 256) {      // 2 * (35 cols * 7 u * 4 short8)
        const bool isV = f >= 980;
        const int g = isV ? f - 980 : f;
        const int col = g / 28;
        const int rem = g - col * 28;
        const int u = rem >> 2, r = rem & 3;
        const __hip_bfloat16* src = (isV ? vbase : kbase) + u * (D * ISTR) + col * JSTR + r * 8;
        short8 s = *(const short8*)src;
        const int colS = (!isV && D == 2) ? ((col >> 1) + (col & 1) * 18) : col;
        short* dst = isV ? Vl : Kl;
        *(short8*)&dst[(colS * 7 + u) * 40 + r * 8] = s;
    }
    if (tid < 169) biasl[tid] = rpb[hsub * 169 + tid];
    if (tid < 52) {
        int uu = tid / 7, vv = tid - uu * 7;
        cpvt[tid] = (tid < 49) ? (D * vv * 7 + uu) * 20 : 0;   // word offsets
    }
    __syncthreads();

    int u = lane / 7, v = lane - u * 7;
    const bool act = lane < 49;
    if (!act) { u = 0; v = 0; }
    const int bconst = u * 13 + v + pbi * 13;
    const int qt = lane >> 4, dp = lane & 15;
    const unsigned* Vw = (const unsigned*)Vl;

    int cpw[13];
#pragma unroll
    for (int t = 0; t < 13; ++t) cpw[t] = cpvt[qt * 13 + t];

    const int j0 = half_ * 28 + wid * 7;

    float qA[32], qB[32];
#define LOADQ(dst, jx)                                                        \
    {                                                                         \
        const short8* qp = (const short8*)(ybase + i * ISTR + (jx) * JSTR);   \
        _Pragma("unroll")                                                     \
        for (int r = 0; r < 4; ++r) {                                         \
            short8 tq = qp[r];                                                \
            const unsigned* tu = (const unsigned*)&tq;                        \
            _Pragma("unroll")                                                 \
            for (int e = 0; e < 4; ++e) {                                     \
                dst[8 * r + 2 * e]     = bf_lo(tu[e]);                        \
                dst[8 * r + 2 * e + 1] = bf_hi(tu[e]);                        \
            }                                                                 \
        }                                                                     \
    }

    auto body = [&](const float (&q)[32], float (&qn)[32], int jj, bool pre) {
        const int j = j0 + jj;
        int wsj, pbj;
        if (D == 1) {
            wsj = (j < 3) ? 0 : ((j > 52) ? 49 : j - 3);
            pbj = (j < 3) ? 6 - j : ((j > 52) ? 55 - j : 3);
        } else {
            wsj = (j < 6) ? (j & 1) : ((j >= 50) ? 42 + (j & 1) : j - 6);
            pbj = (j < 6) ? 6 - (j >> 1) : ((j >= 50) ? (55 - j) >> 1 : 3);
        }
        if (pre) LOADQ(qn, j + 1);
        const int kcol0 = wsj - cmin;

        // QK from bf16 LDS
        int rrl;
        if (D == 1) rrl = (kcol0 + v) * 7 + u;
        else {
            const int kc = kcol0 + 2 * v;
            rrl = ((kc >> 1) + (kc & 1) * 18) * 7 + u;
        }
        const short* kp = &Kl[rrl * 40];
        float acc = 0.f;
#pragma unroll
        for (int s = 0; s < 4; ++s) {
            short8 kk = *(const short8*)(kp + s * 8);
            const unsigned* ku = (const unsigned*)&kk;
#pragma unroll
            for (int e = 0; e < 4; ++e) {
                acc += q[s * 8 + 2 * e]     * bf_lo(ku[e]);
                acc += q[s * 8 + 2 * e + 1] * bf_hi(ku[e]);
            }
        }

        // no-max softmax (logits ~N(0,1): exp exact-safe in f32)
        float e = act ? __expf(acc * SCALE_Q + biasl[bconst + pbj]) : 0.f;
        float ssum = e;
#pragma unroll
        for (int off = 32; off; off >>= 1) ssum += __shfl_xor(ssum, off);
        const float wgt = e * __frcp_rn(ssum);

        // PV from LDS: quarter qt covers positions qt*13 .. qt*13+12
        const int vbw = kcol0 * 140 + dp;    // word base (140 = 7*20)
        float o0 = 0.f, o1 = 0.f;
#pragma unroll
        for (int t = 0; t < 13; ++t) {
            const float wv = __shfl(wgt, qt * 13 + t);
            const unsigned vw = Vw[vbw + cpw[t]];
            o0 += wv * bf_lo(vw);
            o1 += wv * bf_hi(vw);
        }
        o0 += __shfl_xor(o0, 16); o0 += __shfl_xor(o0, 32);
        o1 += __shfl_xor(o1, 16); o1 += __shfl_xor(o1, 32);
        if (lane < 16) {
            union { ushort2 s; unsigned w; } pk;
            pk.s.x = f2bf_bits(o0);
            pk.s.y = f2bf_bits(o1);
            *(unsigned*)&opre[(size_t)b * (SPA * CCH) +
                              (size_t)(i * WID + j) * CCH + head * HD + dp * 2] = pk.w;
        }
    };

    LOADQ(qA, j0);
    body(qA, qB, 0, true);
    body(qB, qA, 1, true);
    body(qA, qB, 2, true);
    body(qB, qA, 3, true);
    body(qA, qB, 4, true);
    body(qB, qA, 5, true);
    body(qA, qB, 6, false);
#undef LOADQ
}

__global__ __launch_bounds__(256) void k_attn5(const __hip_bfloat16* __restrict__ y2,
                                               const float* __restrict__ rpb0,
                                               const float* __restrict__ rpb1,
                                               __hip_bfloat16* __restrict__ opre) {
    __shared__ __align__(16) short Kl[9800];   // 245 rows x 40 shorts
    __shared__ __align__(16) short Vl[9800];
    __shared__ float biasl[169];
    __shared__ int   cpvt[52];
    const int half_ = blockIdx.x;
    const int i = blockIdx.y;
    const int bh = blockIdx.z;
    const int b = bh >> 3, head = bh & 7;
    if (head < 4)
        attn_body<1>(Kl, Vl, biasl, cpvt, y2, rpb0, opre, b, head, i, half_, head);
    else
        attn_body<2>(Kl, Vl, biasl, cpvt, y2, rpb1, opre, b, head, i, half_, head - 4);
}

extern "C" void kernel_launch(void* const* d_in, const int* in_sizes, int n_in,
                              void* d_out, int out_size, void* d_ws, size_t ws_size,
                              hipStream_t stream) {
    const float* x    = (const float*)d_in[0];
    const float* w1   = (const float*)d_in[1];
    const float* w2   = (const float*)d_in[2];
    const float* rpb0 = (const float*)d_in[3];
    const float* rpb1 = (const float*)d_in[4];
    const float* wp   = (const float*)d_in[5];
    float* out = (float*)d_out;

    float* p = (float*)d_ws;
    float* y1 = p;                                       // [2][768][3136] f32
    __hip_bfloat16* y2b  = (__hip_bfloat16*)(p + 2 * YB);  // [2][768][3136] bf16
    __hip_bfloat16* xT   = (__hip_bfloat16*)(p + 3 * YB);  // [2][3136][256] bf16
    __hip_bfloat16* opre = xT;                             // disjoint lifetimes
    __hip_bfloat16* w1b  = (__hip_bfloat16*)(p + 3 * YB + 802816);
    __hip_bfloat16* wpb  = (__hip_bfloat16*)(p + 3 * YB + 802816 + 98304);

    k_cvt<<<dim3(49, 4, 3), 256, 0, stream>>>(x, w1, wp, xT, w1b, wpb);
    k_gemm<<<dim3(49, 12, 2), 256, 0, stream>>>(w1b, xT, y1, C3);
    k_dw<<<dim3(4704), 256, 0, stream>>>(y1, w2, y2b);
    k_attn5<<<dim3(2, HGT, 2 * NH), 256, 0, stream>>>(y2b, rpb0, rpb1, opre);
    k_gemm<<<dim3(49, 4, 2), 256, 0, stream>>>(wpb, opre, out, CCH);
}

// Round 8
// 63.848 us; speedup vs baseline: 3.2244x; 1.0351x over previous
//
#include <hip/hip_runtime.h>
#include <hip/hip_bf16.h>

// Sizes (static per reference)
#define HGT 56
#define WID 56
#define SPA 3136          // 56*56
#define CCH 256
#define C3  768
#define NH  8
#define HD  32
#define YB  2408448       // 768*3136 per-batch elem count
#define ISTR 43008        // 56*768  (reshaped NCHW-flat view: per-i stride)
#define JSTR 768          // per-j stride
#define SCALE_Q 0.17677669529663687f   // 32^-0.5

typedef __attribute__((ext_vector_type(8))) short short8;
typedef __attribute__((ext_vector_type(4))) float f32x4;

static __device__ __forceinline__ unsigned short f2bf_bits(float f) {
    __hip_bfloat16 h = __float2bfloat16(f);
    union { __hip_bfloat16 h; unsigned short u; } cv; cv.h = h; return cv.u;
}
static __device__ __forceinline__ float bf_lo(unsigned u) {
    union { unsigned x; float f; } c; c.x = u << 16; return c.f;
}
static __device__ __forceinline__ float bf_hi(unsigned u) {
    union { unsigned x; float f; } c; c.x = u & 0xffff0000u; return c.f;
}
static __device__ __forceinline__ float bfu(unsigned short u) {
    union { unsigned x; float f; } c; c.x = (unsigned)u << 16; return c.f;
}

// ---------------- cvt: xT (z<2) + weights (z==2) in one dispatch
__global__ __launch_bounds__(256) void k_cvt(const float* __restrict__ x,
                                             const float* __restrict__ w1,
                                             const float* __restrict__ wp,
                                             __hip_bfloat16* __restrict__ xT,
                                             __hip_bfloat16* __restrict__ w1b,
                                             __hip_bfloat16* __restrict__ wpb) {
    __shared__ __align__(16) __hip_bfloat16 Sl[64][80];   // 160B rows
    const int t = threadIdx.x;
    const int z = blockIdx.z;
    if (z == 2) {   // weights: w1 (196608) then wp (65536), grid-stride x4
        const int gid = (blockIdx.y * 49 + blockIdx.x) * 256 + t;
        for (int i = gid * 4; i < 262144; i += 200704) {
            const float* src;
            __hip_bfloat16* dst;
            if (i < 196608) { src = w1 + i; dst = w1b + i; }
            else            { src = wp + (i - 196608); dst = wpb + (i - 196608); }
            float4 v = *(const float4*)src;
            ushort4 u;
            u.x = f2bf_bits(v.x); u.y = f2bf_bits(v.y);
            u.z = f2bf_bits(v.z); u.w = f2bf_bits(v.w);
            *(ushort4*)dst = u;
        }
        return;
    }
    const int b = z, c0 = blockIdx.y * 64, s0 = blockIdx.x * 64;
    const float* xb = x + (size_t)b * (CCH * SPA);
    const int sq = (t & 15) * 4, cq = (t >> 4) * 4;   // 4x4 micro-tile
    float4 r[4];
#pragma unroll
    for (int rr = 0; rr < 4; ++rr)
        r[rr] = *(const float4*)&xb[(size_t)(c0 + cq + rr) * SPA + s0 + sq];
#pragma unroll
    for (int j = 0; j < 4; ++j) {
        ushort4 u;
        u.x = f2bf_bits(((const float*)&r[0])[j]);
        u.y = f2bf_bits(((const float*)&r[1])[j]);
        u.z = f2bf_bits(((const float*)&r[2])[j]);
        u.w = f2bf_bits(((const float*)&r[3])[j]);
        *(ushort4*)&Sl[sq + j][cq] = u;
    }
    __syncthreads();
    const int srow = t >> 2, cslot = t & 3;
    __hip_bfloat16* dst = &xT[(size_t)b * SPA * CCH + (size_t)(s0 + srow) * CCH + c0];
    short8 v0 = *(const short8*)&Sl[srow][cslot * 8];
    short8 v1 = *(const short8*)&Sl[srow][(cslot + 4) * 8];
    *(short8*)&dst[cslot * 8] = v0;
    *(short8*)&dst[(cslot + 4) * 8] = v1;
}

// ---------------- bf16 MFMA GEMM: C[b][o][s] = sum_c A[o][c] * B[b][s][c]
// OBF: write bf16 output (qkv path) vs f32 (final proj)
template<bool OBF>
__global__ __launch_bounds__(256) void k_gemm(const __hip_bfloat16* __restrict__ A,
                                              const __hip_bfloat16* __restrict__ B,
                                              void* __restrict__ Cv, int M) {
    __shared__ __align__(16) short sA[4096];   // 64 rows x 128B, swizzled
    __shared__ __align__(16) short sB[4096];
    const int t = threadIdx.x;
    const int lane = t & 63, w = t >> 6;
    const int s0 = blockIdx.x * 64, o0 = blockIdx.y * 64, b = blockIdx.z;
    const __hip_bfloat16* Bb = B + (size_t)b * SPA * CCH;

    const int srow = t >> 3;
    const int scol = (t & 7) ^ (srow & 7);
    const char* gA = (const char*)(A  + (size_t)(o0 + srow) * CCH) + scol * 16;
    const char* gB = (const char*)(Bb + (size_t)(s0 + srow) * CCH) + scol * 16;
    char* lA = (char*)sA + w * 1024;
    char* lB = (char*)sB + w * 1024;

    const int wm = w >> 1, wn = w & 1;
    const int lr = lane & 15, kh = lane >> 4;
    const int ar0 = wm * 32 + lr, ar1 = ar0 + 16;
    const int br0 = wn * 32 + lr, br1 = br0 + 16;

    f32x4 acc[2][2] = {};
    for (int kt = 0; kt < 4; ++kt) {
        __builtin_amdgcn_global_load_lds(
            (const __attribute__((address_space(1))) void*)(gA + kt * 128),
            (__attribute__((address_space(3))) void*)lA, 16, 0, 0);
        __builtin_amdgcn_global_load_lds(
            (const __attribute__((address_space(1))) void*)(gA + 16384 + kt * 128),
            (__attribute__((address_space(3))) void*)(lA + 4096), 16, 0, 0);
        __builtin_amdgcn_global_load_lds(
            (const __attribute__((address_space(1))) void*)(gB + kt * 128),
            (__attribute__((address_space(3))) void*)lB, 16, 0, 0);
        __builtin_amdgcn_global_load_lds(
            (const __attribute__((address_space(1))) void*)(gB + 16384 + kt * 128),
            (__attribute__((address_space(3))) void*)(lB + 4096), 16, 0, 0);
        __syncthreads();
#pragma unroll
        for (int kk = 0; kk < 2; ++kk) {
            const int kg = (kk << 2) | kh;
            short8 a0 = *(const short8*)&sA[(ar0 * 128 + ((kg ^ (ar0 & 7)) << 4)) >> 1];
            short8 a1 = *(const short8*)&sA[(ar1 * 128 + ((kg ^ (ar1 & 7)) << 4)) >> 1];
            short8 b0 = *(const short8*)&sB[(br0 * 128 + ((kg ^ (br0 & 7)) << 4)) >> 1];
            short8 b1 = *(const short8*)&sB[(br1 * 128 + ((kg ^ (br1 & 7)) << 4)) >> 1];
            acc[0][0] = __builtin_amdgcn_mfma_f32_16x16x32_bf16(a0, b0, acc[0][0], 0, 0, 0);
            acc[0][1] = __builtin_amdgcn_mfma_f32_16x16x32_bf16(a0, b1, acc[0][1], 0, 0, 0);
            acc[1][0] = __builtin_amdgcn_mfma_f32_16x16x32_bf16(a1, b0, acc[1][0], 0, 0, 0);
            acc[1][1] = __builtin_amdgcn_mfma_f32_16x16x32_bf16(a1, b1, acc[1][1], 0, 0, 0);
        }
        __syncthreads();
    }
#pragma unroll
    for (int mi = 0; mi < 2; ++mi)
#pragma unroll
        for (int ni = 0; ni < 2; ++ni) {
            const int r0 = o0 + wm * 32 + mi * 16 + kh * 4;
            const int cc = s0 + wn * 32 + ni * 16 + lr;
            if constexpr (OBF) {
                __hip_bfloat16* Cb = (__hip_bfloat16*)Cv + (size_t)b * M * SPA;
#pragma unroll
                for (int q = 0; q < 4; ++q)
                    Cb[(size_t)(r0 + q) * SPA + cc] = __float2bfloat16(acc[mi][ni][q]);
            } else {
                float* Cb = (float*)Cv + (size_t)b * M * SPA;
#pragma unroll
                for (int q = 0; q < 4; ++q)
                    Cb[(size_t)(r0 + q) * SPA + cc] = acc[mi][ni][q];
            }
        }
}

// ---------------- K2: depthwise 3x3 SAME, x4 along w, bf16 in/out
__global__ __launch_bounds__(256) void k_dw(const __hip_bfloat16* __restrict__ y1,
                                            const float* __restrict__ w2,
                                            __hip_bfloat16* __restrict__ y2) {
    int idx = blockIdx.x * 256 + threadIdx.x;   // 2*768*56*14 = 1204224 (exact)
    int tw = idx % 14;
    int rest = idx / 14;
    int h = rest % HGT;
    int bc = rest / HGT;          // b*768 + ch
    int w0 = tw * 4;
    const __hip_bfloat16* in = y1 + (size_t)bc * SPA;
    const float* wt = w2 + (bc % C3) * 9;
    float a0 = 0.f, a1 = 0.f, a2 = 0.f, a3 = 0.f;
#pragma unroll
    for (int dh = -1; dh <= 1; ++dh) {
        int hh = h + dh;
        if (hh < 0 || hh >= HGT) continue;
        const __hip_bfloat16* rp = in + hh * WID + w0;
        ushort4 c4 = *(const ushort4*)rp;    // 8B aligned (w0 % 4 == 0)
        float c0 = bfu(c4.x), c1 = bfu(c4.y), c2 = bfu(c4.z), c3 = bfu(c4.w);
        float l = (w0 > 0)  ? bfu(*(const unsigned short*)(rp - 1)) : 0.f;
        float r = (w0 < 52) ? bfu(*(const unsigned short*)(rp + 4)) : 0.f;
        float wl = wt[(dh + 1) * 3 + 0];
        float wc = wt[(dh + 1) * 3 + 1];
        float wr = wt[(dh + 1) * 3 + 2];
        a0 += wl * l  + wc * c0 + wr * c1;
        a1 += wl * c0 + wc * c1 + wr * c2;
        a2 += wl * c1 + wc * c2 + wr * c3;
        a3 += wl * c2 + wc * c3 + wr * r;
    }
    ushort4 o;
    o.x = f2bf_bits(a0); o.y = f2bf_bits(a1);
    o.z = f2bf_bits(a2); o.w = f2bf_bits(a3);
    *(ushort4*)(y2 + (size_t)bc * SPA + h * WID + w0) = o;
}

// ---------------- K3 v6: deferred-division softmax + 2-stage software pipeline.
// PHASE1 = QK+exp (pixel j+1) overlaps PHASE2 = PV+reductions+store (pixel j).
template<int D>
__device__ __forceinline__ void attn_body(short* __restrict__ Kl,
                                          short* __restrict__ Vl,
                                          float* __restrict__ biasl,
                                          int* __restrict__ cpvt,
                                          const __hip_bfloat16* __restrict__ y2,
                                          const float* __restrict__ rpb,
                                          __hip_bfloat16* __restrict__ opre,
                                          int b, int head, int i, int half_, int hsub) {
    const int tid = threadIdx.x;
    const int lane = tid & 63, wid = tid >> 6;
    const int cmin = half_ ? 21 : 0;

    int wsi, pbi;
    if (D == 1) {
        wsi = (i < 3) ? 0 : ((i > 52) ? 49 : i - 3);
        pbi = (i < 3) ? 6 - i : ((i > 52) ? 55 - i : 3);
    } else {
        wsi = (i < 6) ? (i & 1) : ((i >= 50) ? 42 + (i & 1) : i - 6);
        pbi = (i < 6) ? 6 - (i >> 1) : ((i >= 50) ? (55 - i) >> 1 : 3);
    }

    const __hip_bfloat16* ybase = y2 + (size_t)b * YB + head * HD;

    // ---- stage K (remapped cols) and V (linear cols); rows = 40 shorts (80B)
    const __hip_bfloat16* kbase = ybase + CCH     + wsi * ISTR + cmin * JSTR;
    const __hip_bfloat16* vbase = ybase + 2 * CCH + wsi * ISTR + cmin * JSTR;
    for (int f = tid; f < 1960; f += 256) {      // 2 * (35 cols * 7 u * 4 short8)
        const bool isV = f >= 980;
        const int g = isV ? f - 980 : f;
        const int col = g / 28;
        const int rem = g - col * 28;
        const int u = rem >> 2, r = rem & 3;
        const __hip_bfloat16* src = (isV ? vbase : kbase) + u * (D * ISTR) + col * JSTR + r * 8;
        short8 s = *(const short8*)src;
        const int colS = (!isV && D == 2) ? ((col >> 1) + (col & 1) * 18) : col;
        short* dst = isV ? Vl : Kl;
        *(short8*)&dst[(colS * 7 + u) * 40 + r * 8] = s;
    }
    if (tid < 169) biasl[tid] = rpb[hsub * 169 + tid];
    if (tid < 52) {
        int uu = tid / 7, vv = tid - uu * 7;
        cpvt[tid] = (tid < 49) ? (D * vv * 7 + uu) * 20 : 0;   // word offsets
    }
    __syncthreads();

    int u = lane / 7, v = lane - u * 7;
    const bool act = lane < 49;
    if (!act) { u = 0; v = 0; }
    const int bconst = u * 13 + v + pbi * 13;
    const int qt = lane >> 4, dp = lane & 15;
    const unsigned* Vw = (const unsigned*)Vl;

    int cpw[13];
#pragma unroll
    for (int t = 0; t < 13; ++t) cpw[t] = cpvt[qt * 13 + t];

    const int j0 = half_ * 28 + wid * 7;
    const size_t obase = (size_t)b * (SPA * CCH) + (size_t)(i * WID) * CCH + head * HD + dp * 2;

    float qA[32], qB[32];
    float eA, eB;
    int kA, kB;

    auto loadq = [&](float (&dst)[32], int jx) {
        const short8* qp = (const short8*)(ybase + i * ISTR + jx * JSTR);
#pragma unroll
        for (int r = 0; r < 4; ++r) {
            short8 tq = qp[r];
            const unsigned* tu = (const unsigned*)&tq;
#pragma unroll
            for (int e = 0; e < 4; ++e) {
                dst[8 * r + 2 * e]     = bf_lo(tu[e]);
                dst[8 * r + 2 * e + 1] = bf_hi(tu[e]);
            }
        }
    };

    // QK + exp (no-max softmax numerator; logits ~N(0,1): exp exact-safe in f32)
    auto phase1 = [&](const float (&q)[32], int j, float& eo, int& ko) {
        int wsj, pbj;
        if (D == 1) {
            wsj = (j < 3) ? 0 : ((j > 52) ? 49 : j - 3);
            pbj = (j < 3) ? 6 - j : ((j > 52) ? 55 - j : 3);
        } else {
            wsj = (j < 6) ? (j & 1) : ((j >= 50) ? 42 + (j & 1) : j - 6);
            pbj = (j < 6) ? 6 - (j >> 1) : ((j >= 50) ? (55 - j) >> 1 : 3);
        }
        const int kcol0 = wsj - cmin;
        ko = kcol0;
        int rrl;
        if (D == 1) rrl = (kcol0 + v) * 7 + u;
        else {
            const int kc = kcol0 + 2 * v;
            rrl = ((kc >> 1) + (kc & 1) * 18) * 7 + u;
        }
        const short* kp = &Kl[rrl * 40];
        float a0 = 0.f, a1 = 0.f;
#pragma unroll
        for (int s = 0; s < 4; ++s) {
            short8 kk = *(const short8*)(kp + s * 8);
            const unsigned* ku = (const unsigned*)&kk;
            float& ac = (s < 2) ? a0 : a1;
#pragma unroll
            for (int e = 0; e < 4; ++e) {
                ac += q[s * 8 + 2 * e]     * bf_lo(ku[e]);
                ac += q[s * 8 + 2 * e + 1] * bf_hi(ku[e]);
            }
        }
        eo = act ? __expf((a0 + a1) * SCALE_Q + biasl[bconst + pbj]) : 0.f;
    };

    // PV with raw e; ssum reduce runs CONCURRENT with PV (deferred division)
    auto phase2 = [&](float ev, int kc, int jx) {
        const int vbw = kc * 140 + dp;    // word base (140 = 7*20)
        float o0 = 0.f, o1 = 0.f;
#pragma unroll
        for (int t = 0; t < 13; ++t) {
            const float wv = __shfl(ev, qt * 13 + t);
            const unsigned vw = Vw[vbw + cpw[t]];
            o0 += wv * bf_lo(vw);
            o1 += wv * bf_hi(vw);
        }
        float ssum = ev;
#pragma unroll
        for (int off = 32; off; off >>= 1) ssum += __shfl_xor(ssum, off);
        o0 += __shfl_xor(o0, 16); o0 += __shfl_xor(o0, 32);
        o1 += __shfl_xor(o1, 16); o1 += __shfl_xor(o1, 32);
        const float rinv = __frcp_rn(ssum);
        if (lane < 16) {
            union { ushort2 s; unsigned w; } pk;
            pk.s.x = f2bf_bits(o0 * rinv);
            pk.s.y = f2bf_bits(o1 * rinv);
            *(unsigned*)&opre[obase + (size_t)jx * CCH] = pk.w;
        }
    };

    loadq(qA, j0);          phase1(qA, j0,     eA, kA);
    loadq(qB, j0 + 1);      phase1(qB, j0 + 1, eB, kB);  phase2(eA, kA, j0);
    loadq(qA, j0 + 2);      phase1(qA, j0 + 2, eA, kA);  phase2(eB, kB, j0 + 1);
    loadq(qB, j0 + 3);      phase1(qB, j0 + 3, eB, kB);  phase2(eA, kA, j0 + 2);
    loadq(qA, j0 + 4);      phase1(qA, j0 + 4, eA, kA);  phase2(eB, kB, j0 + 3);
    loadq(qB, j0 + 5);      phase1(qB, j0 + 5, eB, kB);  phase2(eA, kA, j0 + 4);
    loadq(qA, j0 + 6);      phase1(qA, j0 + 6, eA, kA);  phase2(eB, kB, j0 + 5);
    phase2(eA, kA, j0 + 6);
}

__global__ __launch_bounds__(256) void k_attn6(const __hip_bfloat16* __restrict__ y2,
                                               const float* __restrict__ rpb0,
                                               const float* __restrict__ rpb1,
                                               __hip_bfloat16* __restrict__ opre) {
    __shared__ __align__(16) short Kl[9800];   // 245 rows x 40 shorts
    __shared__ __align__(16) short Vl[9800];
    __shared__ float biasl[169];
    __shared__ int   cpvt[52];
    const int half_ = blockIdx.x;
    const int i = blockIdx.y;
    const int bh = blockIdx.z;
    const int b = bh >> 3, head = bh & 7;
    if (head < 4)
        attn_body<1>(Kl, Vl, biasl, cpvt, y2, rpb0, opre, b, head, i, half_, head);
    else
        attn_body<2>(Kl, Vl, biasl, cpvt, y2, rpb1, opre, b, head, i, half_, head - 4);
}

extern "C" void kernel_launch(void* const* d_in, const int* in_sizes, int n_in,
                              void* d_out, int out_size, void* d_ws, size_t ws_size,
                              hipStream_t stream) {
    const float* x    = (const float*)d_in[0];
    const float* w1   = (const float*)d_in[1];
    const float* w2   = (const float*)d_in[2];
    const float* rpb0 = (const float*)d_in[3];
    const float* rpb1 = (const float*)d_in[4];
    const float* wp   = (const float*)d_in[5];
    float* out = (float*)d_out;

    float* p = (float*)d_ws;
    __hip_bfloat16* y1b  = (__hip_bfloat16*)p;             // [2][768][3136] bf16 (YB f32 slots)
    __hip_bfloat16* y2b  = (__hip_bfloat16*)(p + YB);      // [2][768][3136] bf16
    __hip_bfloat16* xT   = (__hip_bfloat16*)(p + 2 * YB);  // [2][3136][256] bf16
    __hip_bfloat16* opre = xT;                             // disjoint lifetimes
    __hip_bfloat16* w1b  = (__hip_bfloat16*)(p + 2 * YB + 802816);
    __hip_bfloat16* wpb  = (__hip_bfloat16*)(p + 2 * YB + 802816 + 98304);

    k_cvt<<<dim3(49, 4, 3), 256, 0, stream>>>(x, w1, wp, xT, w1b, wpb);
    k_gemm<true><<<dim3(49, 12, 2), 256, 0, stream>>>(w1b, xT, (void*)y1b, C3);
    k_dw<<<dim3(4704), 256, 0, stream>>>(y1b, w2, y2b);
    k_attn6<<<dim3(2, HGT, 2 * NH), 256, 0, stream>>>(y2b, rpb0, rpb1, opre);
    k_gemm<false><<<dim3(49, 4, 2), 256, 0, stream>>>(wpb, opre, (void*)out, CCH);
}

// Round 11
// 58.527 us; speedup vs baseline: 3.5176x; 1.0909x over previous
//
#include <hip/hip_runtime.h>
#include <hip/hip_bf16.h>

// Sizes (static per reference)
#define HGT 56
#define WID 56
#define SPA 3136          // 56*56
#define CCH 256
#define C3  768
#define NH  8
#define HD  32
#define YB  2408448       // 768*3136 per-batch elem count
#define ISTR 43008        // 56*768  (reshaped NCHW-flat view: per-i stride)
#define JSTR 768          // per-j stride
#define SCALE_Q 0.17677669529663687f   // 32^-0.5

typedef __attribute__((ext_vector_type(8))) short short8;
typedef __attribute__((ext_vector_type(4))) float f32x4;

static __device__ __forceinline__ unsigned short f2bf_bits(float f) {
    __hip_bfloat16 h = __float2bfloat16(f);
    union { __hip_bfloat16 h; unsigned short u; } cv; cv.h = h; return cv.u;
}
static __device__ __forceinline__ float bf_lo(unsigned u) {
    union { unsigned x; float f; } c; c.x = u << 16; return c.f;
}
static __device__ __forceinline__ float bf_hi(unsigned u) {
    union { unsigned x; float f; } c; c.x = u & 0xffff0000u; return c.f;
}
static __device__ __forceinline__ float bfu(unsigned short u) {
    union { unsigned x; float f; } c; c.x = (unsigned)u << 16; return c.f;
}
static __device__ __forceinline__ unsigned pk2bf(float a, float b) {
    return ((unsigned)f2bf_bits(b) << 16) | (unsigned)f2bf_bits(a);
}

// ---------------- cvt: xT (z<2) + weights (z==2) in one dispatch
__global__ __launch_bounds__(256) void k_cvt(const float* __restrict__ x,
                                             const float* __restrict__ w1,
                                             const float* __restrict__ wp,
                                             __hip_bfloat16* __restrict__ xT,
                                             __hip_bfloat16* __restrict__ w1b,
                                             __hip_bfloat16* __restrict__ wpb) {
    __shared__ __align__(16) __hip_bfloat16 Sl[64][80];   // 160B rows
    const int t = threadIdx.x;
    const int z = blockIdx.z;
    if (z == 2) {   // weights: w1 (196608) then wp (65536), grid-stride x4
        const int gid = (blockIdx.y * 49 + blockIdx.x) * 256 + t;
        for (int i = gid * 4; i < 262144; i += 200704) {
            const float* src;
            __hip_bfloat16* dst;
            if (i < 196608) { src = w1 + i; dst = w1b + i; }
            else            { src = wp + (i - 196608); dst = wpb + (i - 196608); }
            float4 v = *(const float4*)src;
            ushort4 u;
            u.x = f2bf_bits(v.x); u.y = f2bf_bits(v.y);
            u.z = f2bf_bits(v.z); u.w = f2bf_bits(v.w);
            *(ushort4*)dst = u;
        }
        return;
    }
    const int b = z, c0 = blockIdx.y * 64, s0 = blockIdx.x * 64;
    const float* xb = x + (size_t)b * (CCH * SPA);
    const int sq = (t & 15) * 4, cq = (t >> 4) * 4;   // 4x4 micro-tile
    float4 r[4];
#pragma unroll
    for (int rr = 0; rr < 4; ++rr)
        r[rr] = *(const float4*)&xb[(size_t)(c0 + cq + rr) * SPA + s0 + sq];
#pragma unroll
    for (int j = 0; j < 4; ++j) {
        ushort4 u;
        u.x = f2bf_bits(((const float*)&r[0])[j]);
        u.y = f2bf_bits(((const float*)&r[1])[j]);
        u.z = f2bf_bits(((const float*)&r[2])[j]);
        u.w = f2bf_bits(((const float*)&r[3])[j]);
        *(ushort4*)&Sl[sq + j][cq] = u;
    }
    __syncthreads();
    const int srow = t >> 2, cslot = t & 3;
    __hip_bfloat16* dst = &xT[(size_t)b * SPA * CCH + (size_t)(s0 + srow) * CCH + c0];
    short8 v0 = *(const short8*)&Sl[srow][cslot * 8];
    short8 v1 = *(const short8*)&Sl[srow][(cslot + 4) * 8];
    *(short8*)&dst[cslot * 8] = v0;
    *(short8*)&dst[(cslot + 4) * 8] = v1;
}

// ---------------- bf16 MFMA GEMM: C[b][o][s] = sum_c A[o][c] * B[b][s][c]
template<bool OBF>
__global__ __launch_bounds__(256) void k_gemm(const __hip_bfloat16* __restrict__ A,
                                              const __hip_bfloat16* __restrict__ B,
                                              void* __restrict__ Cv, int M) {
    __shared__ __align__(16) short sA[4096];   // 64 rows x 128B, swizzled
    __shared__ __align__(16) short sB[4096];
    const int t = threadIdx.x;
    const int lane = t & 63, w = t >> 6;
    const int s0 = blockIdx.x * 64, o0 = blockIdx.y * 64, b = blockIdx.z;
    const __hip_bfloat16* Bb = B + (size_t)b * SPA * CCH;

    const int srow = t >> 3;
    const int scol = (t & 7) ^ (srow & 7);
    const char* gA = (const char*)(A  + (size_t)(o0 + srow) * CCH) + scol * 16;
    const char* gB = (const char*)(Bb + (size_t)(s0 + srow) * CCH) + scol * 16;
    char* lA = (char*)sA + w * 1024;
    char* lB = (char*)sB + w * 1024;

    const int wm = w >> 1, wn = w & 1;
    const int lr = lane & 15, kh = lane >> 4;
    const int ar0 = wm * 32 + lr, ar1 = ar0 + 16;
    const int br0 = wn * 32 + lr, br1 = br0 + 16;

    f32x4 acc[2][2] = {};
    for (int kt = 0; kt < 4; ++kt) {
        __builtin_amdgcn_global_load_lds(
            (const __attribute__((address_space(1))) void*)(gA + kt * 128),
            (__attribute__((address_space(3))) void*)lA, 16, 0, 0);
        __builtin_amdgcn_global_load_lds(
            (const __attribute__((address_space(1))) void*)(gA + 16384 + kt * 128),
            (__attribute__((address_space(3))) void*)(lA + 4096), 16, 0, 0);
        __builtin_amdgcn_global_load_lds(
            (const __attribute__((address_space(1))) void*)(gB + kt * 128),
            (__attribute__((address_space(3))) void*)lB, 16, 0, 0);
        __builtin_amdgcn_global_load_lds(
            (const __attribute__((address_space(1))) void*)(gB + 16384 + kt * 128),
            (__attribute__((address_space(3))) void*)(lB + 4096), 16, 0, 0);
        __syncthreads();
#pragma unroll
        for (int kk = 0; kk < 2; ++kk) {
            const int kg = (kk << 2) | kh;
            short8 a0 = *(const short8*)&sA[(ar0 * 128 + ((kg ^ (ar0 & 7)) << 4)) >> 1];
            short8 a1 = *(const short8*)&sA[(ar1 * 128 + ((kg ^ (ar1 & 7)) << 4)) >> 1];
            short8 b0 = *(const short8*)&sB[(br0 * 128 + ((kg ^ (br0 & 7)) << 4)) >> 1];
            short8 b1 = *(const short8*)&sB[(br1 * 128 + ((kg ^ (br1 & 7)) << 4)) >> 1];
            acc[0][0] = __builtin_amdgcn_mfma_f32_16x16x32_bf16(a0, b0, acc[0][0], 0, 0, 0);
            acc[0][1] = __builtin_amdgcn_mfma_f32_16x16x32_bf16(a0, b1, acc[0][1], 0, 0, 0);
            acc[1][0] = __builtin_amdgcn_mfma_f32_16x16x32_bf16(a1, b0, acc[1][0], 0, 0, 0);
            acc[1][1] = __builtin_amdgcn_mfma_f32_16x16x32_bf16(a1, b1, acc[1][1], 0, 0, 0);
        }
        __syncthreads();
    }
#pragma unroll
    for (int mi = 0; mi < 2; ++mi)
#pragma unroll
        for (int ni = 0; ni < 2; ++ni) {
            const int r0 = o0 + wm * 32 + mi * 16 + kh * 4;
            const int cc = s0 + wn * 32 + ni * 16 + lr;
            if constexpr (OBF) {
                __hip_bfloat16* Cb = (__hip_bfloat16*)Cv + (size_t)b * M * SPA;
#pragma unroll
                for (int q = 0; q < 4; ++q)
                    Cb[(size_t)(r0 + q) * SPA + cc] = __float2bfloat16(acc[mi][ni][q]);
            } else {
                float* Cb = (float*)Cv + (size_t)b * M * SPA;
#pragma unroll
                for (int q = 0; q < 4; ++q)
                    Cb[(size_t)(r0 + q) * SPA + cc] = acc[mi][ni][q];
            }
        }
}

// ---------------- K2: depthwise 3x3 SAME, x4 along w, bf16 in/out
__global__ __launch_bounds__(256) void k_dw(const __hip_bfloat16* __restrict__ y1,
                                            const float* __restrict__ w2,
                                            __hip_bfloat16* __restrict__ y2) {
    int idx = blockIdx.x * 256 + threadIdx.x;   // 2*768*56*14 = 1204224 (exact)
    int tw = idx % 14;
    int rest = idx / 14;
    int h = rest % HGT;
    int bc = rest / HGT;          // b*768 + ch
    int w0 = tw * 4;
    const __hip_bfloat16* in = y1 + (size_t)bc * SPA;
    const float* wt = w2 + (bc % C3) * 9;
    float a0 = 0.f, a1 = 0.f, a2 = 0.f, a3 = 0.f;
#pragma unroll
    for (int dh = -1; dh <= 1; ++dh) {
        int hh = h + dh;
        if (hh < 0 || hh >= HGT) continue;
        const __hip_bfloat16* rp = in + hh * WID + w0;
        ushort4 c4 = *(const ushort4*)rp;
        float c0 = bfu(c4.x), c1 = bfu(c4.y), c2 = bfu(c4.z), c3 = bfu(c4.w);
        float l = (w0 > 0)  ? bfu(*(const unsigned short*)(rp - 1)) : 0.f;
        float r = (w0 < 52) ? bfu(*(const unsigned short*)(rp + 4)) : 0.f;
        float wl = wt[(dh + 1) * 3 + 0];
        float wc = wt[(dh + 1) * 3 + 1];
        float wr = wt[(dh + 1) * 3 + 2];
        a0 += wl * l  + wc * c0 + wr * c1;
        a1 += wl * c0 + wc * c1 + wr * c2;
        a2 += wl * c1 + wc * c2 + wr * c3;
        a3 += wl * c2 + wc * c3 + wr * r;
    }
    ushort4 o;
    o.x = f2bf_bits(a0); o.y = f2bf_bits(a1);
    o.z = f2bf_bits(a2); o.w = f2bf_bits(a3);
    *(ushort4*)(y2 + (size_t)bc * SPA + h * WID + w0) = o;
}

// ---------------- K3 v7c: MFMA attention. One block per (b,head,i), 4 waves.
// v7c fix: ssum is a PARTIAL sum per lane (lane holds only kj = Mt*16+kh*4+q);
// full column denominator needs reduction across the 4 kh groups:
// shfl_xor 16 and 32 (lanes {lr, lr+16, lr+32, lr+48} share the same j).
template<int D>
__device__ __forceinline__ void attn7_body(short* __restrict__ sK,
                                           short* __restrict__ sVT,
                                           short* __restrict__ sQ,
                                           short* __restrict__ sP,
                                           float* __restrict__ sEB,
                                           const __hip_bfloat16* __restrict__ y2,
                                           const float* __restrict__ rpb,
                                           __hip_bfloat16* __restrict__ opre,
                                           int b, int head, int i, int hsub) {
    const int tid = threadIdx.x;
    const int lane = tid & 63, w = tid >> 6;
    const int lr = lane & 15, kh = lane >> 4;

    int wsi, pbi;
    if (D == 1) {
        wsi = (i < 3) ? 0 : ((i > 52) ? 49 : i - 3);
        pbi = (i < 3) ? 6 - i : ((i > 52) ? 55 - i : 3);
    } else {
        wsi = (i < 6) ? (i & 1) : ((i >= 50) ? 42 + (i & 1) : i - 6);
        pbi = (i < 6) ? 6 - (i >> 1) : ((i >= 50) ? (55 - i) >> 1 : 3);
    }

    const __hip_bfloat16* base  = y2 + (size_t)b * YB + head * HD;
    const __hip_bfloat16* kbase = base + CCH     + wsi * ISTR;
    const __hip_bfloat16* vbase = base + 2 * CCH + wsi * ISTR;
    const __hip_bfloat16* qbase = base + i * ISTR;

    // ---- K stage: [u 7][kj 64][d 32], rows 64B = 4x16B slots, XOR key kj&3,
    // pre-swizzled global source; kj>=56 source clamped to col 55 (masked later).
    for (int f = tid; f < 1792; f += 256) {       // 7*64*4, exact multiple of 256
        int u = f >> 8, rem = f & 255, kj = rem >> 2, slot = rem & 3;
        int kjc = (kj > 55) ? 55 : kj;            // clamp source col (LDS row stays kj)
        const __hip_bfloat16* src = kbase + u * (D * ISTR) + kjc * JSTR + ((slot ^ (kj & 3)) << 3);
        char* dst = (char*)sK + (size_t)(f - lane) * 16;
        __builtin_amdgcn_global_load_lds(
            (const __attribute__((address_space(1))) void*)src,
            (__attribute__((address_space(3))) void*)dst, 16, 0, 0);
    }
    // ---- Q stage: [j 64][d 32], same swizzle; rows >=56 clamped (unused)
    {
        int jq = tid >> 2, slot = tid & 3;
        int jqc = (jq > 55) ? 55 : jq;
        const __hip_bfloat16* src = qbase + jqc * JSTR + ((slot ^ (jq & 3)) << 3);
        char* dst = (char*)sQ + (size_t)(tid - lane) * 16;
        __builtin_amdgcn_global_load_lds(
            (const __attribute__((address_space(1))) void*)src,
            (__attribute__((address_space(3))) void*)dst, 16, 0, 0);
    }
    // ---- V^T stage: [u 7][d 32][kj 64], rows 128B = 8x16B groups, XOR key d&7.
    for (int f = tid; f < 1568; f += 256) {       // 7 * 8 dq * 28 kjp
        int u = f / 224, rem = f - u * 224;
        int dq = rem / 28, kjp = rem - dq * 28;
        const __hip_bfloat16* g0 = vbase + u * (D * ISTR) + (2 * kjp) * JSTR + dq * 4;
        ushort4 va = *(const ushort4*)g0;
        ushort4 vb = *(const ushort4*)(g0 + JSTR);
#pragma unroll
        for (int e = 0; e < 4; ++e) {
            int d = dq * 4 + e;
            unsigned pk = ((unsigned)((&vb.x)[e]) << 16) | (unsigned)((&va.x)[e]);
            int row = u * 32 + d;
            int byt = row * 128 + ((((kjp >> 2) ^ (d & 7)) << 4)) + (kjp & 3) * 4;
            *(unsigned*)((char*)sVT + byt) = pk;
        }
    }
    // ---- V^T pad (kj 56..63) = 0  (group 7, swizzled)
    if (tid < 224) {
        int u = tid >> 5, d = tid & 31;
        int row = u * 32 + d;
        int byt = row * 128 + ((7 ^ (d & 7)) << 4);
        *(short8*)((char*)sVT + byt) = (short8){0, 0, 0, 0, 0, 0, 0, 0};
    }
    // ---- EB table: exp(bias) for rows pbi..pbi+6
    if (tid < 91) {
        int u = tid / 13, r = tid - u * 13;
        sEB[tid] = __expf(rpb[hsub * 169 + (pbi + u) * 13 + r]);
    }
    __syncthreads();

    const int j = w * 16 + lr;    // this lane's output column (56..63 invalid)
    int wsj;
    if (D == 1) wsj = (j < 3) ? 0 : ((j > 52) ? 49 : j - 3);
    else        wsj = (j < 6) ? (j & 1) : ((j >= 50) ? 42 + (j & 1) : j - 6);

    // Q B-fragment (hoisted; constant across u)
    short8 qf = *(const short8*)((char*)sQ + j * 64 + ((kh ^ (j & 3)) << 4));

    float ssum = 0.f;
    f32x4 oacc0 = {0.f, 0.f, 0.f, 0.f};
    f32x4 oacc1 = {0.f, 0.f, 0.f, 0.f};
    short* sPw = sP + w * 2048;   // per-wave: 2 buffers x 1024 shorts (2KB each)

#pragma unroll
    for (int u = 0; u < 7; ++u) {
        char* sPb = (char*)(sPw + (u & 1) * 1024);
        // ---- QK: S^T = K * Q^T
        f32x4 s[4];
#pragma unroll
        for (int Mt = 0; Mt < 4; ++Mt) {
            int kjrow = u * 64 + Mt * 16 + lr;
            short8 kf = *(const short8*)((char*)sK + kjrow * 64 + ((kh ^ (lr & 3)) << 4));
            s[Mt] = __builtin_amdgcn_mfma_f32_16x16x32_bf16(kf, qf,
                        (f32x4){0.f, 0.f, 0.f, 0.f}, 0, 0, 0);
        }
        // ---- mask + bias-exp + pack P
#pragma unroll
        for (int Mt = 0; Mt < 4; ++Mt) {
            const int kjb = Mt * 16 + (kh << 2);
            float ev[4];
#pragma unroll
            for (int q = 0; q < 4; ++q) {
                int kj = kjb + q;
                int rel = kj - j;
                int din = kj - wsj;
                bool valid = (din >= 0) && (din <= 6 * D);
                if (D == 2) valid = valid && ((rel & 1) == 0);
                int r = (D == 1) ? (rel + 6) : ((rel >> 1) + 6);
                r = r < 0 ? 0 : (r > 12 ? 12 : r);
                float ex = __expf(s[Mt][q] * SCALE_Q) * sEB[u * 13 + r];
                ev[q] = valid ? ex : 0.f;
                ssum += ev[q];
            }
            uint2 pk2;
            pk2.x = pk2bf(ev[0], ev[1]);
            pk2.y = pk2bf(ev[2], ev[3]);
            int g = Mt * 2 + (kh >> 1);
            int byt = lr * 128 + (((g ^ (lr & 7)) << 4)) + (kh & 1) * 8;
            *(uint2*)(sPb + byt) = pk2;
        }
        // ---- fence: order P-pack writes before PV fragment reads
        __syncthreads();
        // ---- PV: O^T += V^T * P^T
#pragma unroll
        for (int Kt = 0; Kt < 2; ++Kt) {
            short8 pf = *(const short8*)(sPb + lr * 128 + ((((Kt * 4 + kh) ^ (lr & 7)) << 4)));
            {
                int row = u * 32 + lr;            // Mt=0: d = lr
                short8 vf = *(const short8*)((char*)sVT + row * 128 +
                              ((((Kt * 4 + kh) ^ (lr & 7)) << 4)));
                oacc0 = __builtin_amdgcn_mfma_f32_16x16x32_bf16(vf, pf, oacc0, 0, 0, 0);
            }
            {
                int row = u * 32 + 16 + lr;       // Mt=1: d = 16+lr
                short8 vf = *(const short8*)((char*)sVT + row * 128 +
                              ((((Kt * 4 + kh) ^ (lr & 7)) << 4)));
                oacc1 = __builtin_amdgcn_mfma_f32_16x16x32_bf16(vf, pf, oacc1, 0, 0, 0);
            }
        }
    }

    // full softmax denominator: combine the 4 kh-group partials (same j = lr)
    ssum += __shfl_xor(ssum, 16);
    ssum += __shfl_xor(ssum, 32);

    if (j < 56) {
        const float rinv = __frcp_rn(ssum);
        const size_t ob = (size_t)b * (SPA * CCH) + (size_t)(i * WID + j) * CCH
                          + head * HD + (kh << 2);
        uint2 p0, p1;
        p0.x = pk2bf(oacc0[0] * rinv, oacc0[1] * rinv);
        p0.y = pk2bf(oacc0[2] * rinv, oacc0[3] * rinv);
        p1.x = pk2bf(oacc1[0] * rinv, oacc1[1] * rinv);
        p1.y = pk2bf(oacc1[2] * rinv, oacc1[3] * rinv);
        *(uint2*)&opre[ob]      = p0;   // d = kh*4 .. +3
        *(uint2*)&opre[ob + 16] = p1;   // d = 16 + kh*4 .. +3
    }
}

__global__ __launch_bounds__(256) void k_attn7(const __hip_bfloat16* __restrict__ y2,
                                               const float* __restrict__ rpb0,
                                               const float* __restrict__ rpb1,
                                               __hip_bfloat16* __restrict__ opre) {
    __shared__ __align__(16) short sK[14336];    // 28KB
    __shared__ __align__(16) short sVT[14336];   // 28KB
    __shared__ __align__(16) short sQ[2048];     // 4KB
    __shared__ __align__(16) short sP[8192];     // 16KB (4 waves x 2 bufs)
    __shared__ float sEB[91];
    const int i = blockIdx.x;
    const int bh = blockIdx.y;
    const int b = bh >> 3, head = bh & 7;
    if (head < 4)
        attn7_body<1>(sK, sVT, sQ, sP, sEB, y2, rpb0, opre, b, head, i, head);
    else
        attn7_body<2>(sK, sVT, sQ, sP, sEB, y2, rpb1, opre, b, head, i, head - 4);
}

extern "C" void kernel_launch(void* const* d_in, const int* in_sizes, int n_in,
                              void* d_out, int out_size, void* d_ws, size_t ws_size,
                              hipStream_t stream) {
    const float* x    = (const float*)d_in[0];
    const float* w1   = (const float*)d_in[1];
    const float* w2   = (const float*)d_in[2];
    const float* rpb0 = (const float*)d_in[3];
    const float* rpb1 = (const float*)d_in[4];
    const float* wp   = (const float*)d_in[5];
    float* out = (float*)d_out;

    float* p = (float*)d_ws;
    __hip_bfloat16* y1b  = (__hip_bfloat16*)p;             // [2][768][3136] bf16
    __hip_bfloat16* y2b  = (__hip_bfloat16*)(p + YB);      // [2][768][3136] bf16
    __hip_bfloat16* xT   = (__hip_bfloat16*)(p + 2 * YB);  // [2][3136][256] bf16
    __hip_bfloat16* opre = xT;                             // disjoint lifetimes
    __hip_bfloat16* w1b  = (__hip_bfloat16*)(p + 2 * YB + 802816);
    __hip_bfloat16* wpb  = (__hip_bfloat16*)(p + 2 * YB + 802816 + 98304);

    k_cvt<<<dim3(49, 4, 3), 256, 0, stream>>>(x, w1, wp, xT, w1b, wpb);
    k_gemm<true><<<dim3(49, 12, 2), 256, 0, stream>>>(w1b, xT, (void*)y1b, C3);
    k_dw<<<dim3(4704), 256, 0, stream>>>(y1b, w2, y2b);
    k_attn7<<<dim3(HGT, 2 * NH), 256, 0, stream>>>(y2b, rpb0, rpb1, opre);
    k_gemm<false><<<dim3(49, 4, 2), 256, 0, stream>>>(wpb, opre, (void*)out, CCH);
}